// Round 1
// baseline (1935.553 us; speedup 1.0000x reference)
//
#include <hip/hip_runtime.h>

#define N_NODES 50000
#define N_EDGES 800000
#define EMB 128
#define NFEAT 9
#define VOCAB 119
#define NITER 10
#define ALPHA 0.1f

// ---------------- CSR build ----------------

__global__ void k_zero(int* __restrict__ cnt, int* __restrict__ cursor) {
    int i = blockIdx.x * blockDim.x + threadIdx.x;
    if (i < N_NODES) { cnt[i] = 0; cursor[i] = 0; }
}

__global__ void k_count(const int* __restrict__ dst, int* __restrict__ cnt) {
    int e = blockIdx.x * blockDim.x + threadIdx.x;
    if (e < N_EDGES) atomicAdd(&cnt[dst[e]], 1);
}

__global__ void k_dinv(const int* __restrict__ cnt, float* __restrict__ dinv) {
    int v = blockIdx.x * blockDim.x + threadIdx.x;
    if (v < N_NODES) dinv[v] = rsqrtf((float)(cnt[v] + 1));  // +1 self loop
}

// Exclusive scan of cnt -> rowptr (3-kernel hierarchical scan, 256/block)
__global__ void k_scan1(const int* __restrict__ cnt, int* __restrict__ rowptr,
                        int* __restrict__ bsum) {
    __shared__ int s[256];
    int t = threadIdx.x;
    int idx = blockIdx.x * 256 + t;
    int v = (idx < N_NODES) ? cnt[idx] : 0;
    s[t] = v; __syncthreads();
    for (int off = 1; off < 256; off <<= 1) {
        int add = (t >= off) ? s[t - off] : 0;
        __syncthreads();
        s[t] += add;
        __syncthreads();
    }
    if (idx < N_NODES) rowptr[idx] = s[t] - v;   // exclusive
    if (t == 255) bsum[blockIdx.x] = s[255];     // block total
}

__global__ void k_scan2(int* __restrict__ bsum, int nb) {
    __shared__ int s[256];
    int t = threadIdx.x;
    int v = (t < nb) ? bsum[t] : 0;
    s[t] = v; __syncthreads();
    for (int off = 1; off < 256; off <<= 1) {
        int add = (t >= off) ? s[t - off] : 0;
        __syncthreads();
        s[t] += add;
        __syncthreads();
    }
    if (t < nb) bsum[t] = s[t] - v;              // exclusive block offsets
}

__global__ void k_scan3(int* __restrict__ rowptr, const int* __restrict__ bsum) {
    int idx = blockIdx.x * 256 + threadIdx.x;
    if (idx < N_NODES) rowptr[idx] += bsum[blockIdx.x];
}

__global__ void k_fill(const int* __restrict__ src, const int* __restrict__ dst,
                       const int* __restrict__ rowptr, int* __restrict__ cursor,
                       int* __restrict__ csr_src) {
    int e = blockIdx.x * blockDim.x + threadIdx.x;
    if (e < N_EDGES) {
        int v = dst[e];
        int pos = rowptr[v] + atomicAdd(&cursor[v], 1);
        csr_src[pos] = src[e];
    }
}

// ---------------- encoder + MLP ----------------

// 2 nodes per 256-thread block: thread = (sub, d)
__global__ void k_encode(const int* __restrict__ x, const float* __restrict__ emb,
                         float* __restrict__ out) {
    int t = threadIdx.x;
    int d = t & 127, sub = t >> 7;
    int n = blockIdx.x * 2 + sub;
    if (n >= N_NODES) return;
    const int* xr = x + n * NFEAT;
    float s = 0.f;
#pragma unroll
    for (int f = 0; f < NFEAT; ++f) {
        int id = xr[f];
        s += emb[(f * VOCAB + id) * EMB + d];
    }
    out[n * EMB + d] = s;
}

template <int RELU>
__global__ __launch_bounds__(256) void k_mlp(const float* __restrict__ in,
                                             float* __restrict__ out,
                                             const float* __restrict__ W,
                                             const float* __restrict__ b) {
    __shared__ float Wl[EMB * EMB];   // 64 KB
    __shared__ float hs[2][EMB];
    int t = threadIdx.x;
    for (int i = t; i < EMB * EMB; i += 256) Wl[i] = W[i];
    int d = t & 127, sub = t >> 7;
    float bias = b[d];
    __syncthreads();
    // N_NODES is even and n0 is even -> no bounds check needed on n
    for (int n0 = blockIdx.x * 2; n0 < N_NODES; n0 += gridDim.x * 2) {
        int n = n0 + sub;
        hs[sub][d] = in[n * EMB + d];
        __syncthreads();
        float acc = bias;
#pragma unroll 8
        for (int k = 0; k < EMB; ++k) acc += hs[sub][k] * Wl[k * EMB + d];
        if (RELU) acc = fmaxf(acc, 0.f);
        out[n * EMB + d] = acc;
        __syncthreads();
    }
}

// ---------------- propagation ----------------

__global__ __launch_bounds__(256) void k_prop(const float* __restrict__ hin,
                                              const float* __restrict__ h0,
                                              float* __restrict__ hout,
                                              const int* __restrict__ rowptr,
                                              const int* __restrict__ cnt,
                                              const int* __restrict__ csr_src,
                                              const float* __restrict__ dinv) {
    int t = threadIdx.x;
    int d = t & 127, sub = t >> 7;
    int v = blockIdx.x * 2 + sub;
    if (v >= N_NODES) return;
    int start = rowptr[v];
    int c = cnt[v];
    float acc = 0.f;
    for (int i = 0; i < c; ++i) {
        int s = csr_src[start + i];           // broadcast across the 128 threads
        acc += dinv[s] * hin[s * EMB + d];    // coalesced 512B row gather
    }
    float dv = dinv[v];
    float val = (1.f - ALPHA) * (dv * acc + dv * dv * hin[v * EMB + d])
              + ALPHA * h0[v * EMB + d];
    hout[v * EMB + d] = val;
}

// ---------------- host ----------------

extern "C" void kernel_launch(void* const* d_in, const int* in_sizes, int n_in,
                              void* d_out, int out_size, void* d_ws, size_t ws_size,
                              hipStream_t stream) {
    const int*   x    = (const int*)d_in[0];             // [N, 9]
    const int*   ei   = (const int*)d_in[1];             // [2, E]
    const float* emb  = (const float*)d_in[2];           // [9, 119, 128]
    const float* Ws   = (const float*)d_in[3];           // [3, 128, 128]
    const float* bs   = (const float*)d_in[4];           // [3, 128]
    float* out = (float*)d_out;                          // [N, 128] f32

    const int* src = ei;
    const int* dst = ei + N_EDGES;

    // workspace carve-up (all 4-byte elems)
    char* w = (char*)d_ws;
    size_t off = 0;
    auto alloc = [&](size_t elems) { void* p = w + off; off += elems * 4; return p; };
    float* h0      = (float*)alloc((size_t)N_NODES * EMB);
    float* hA      = (float*)alloc((size_t)N_NODES * EMB);
    float* hB      = (float*)alloc((size_t)N_NODES * EMB);
    float* dinv    = (float*)alloc(N_NODES);
    int*   cnt     = (int*)alloc(N_NODES);
    int*   cursor  = (int*)alloc(N_NODES);
    int*   rowptr  = (int*)alloc(N_NODES);
    int*   bsum    = (int*)alloc(256);
    int*   csr_src = (int*)alloc(N_EDGES);
    (void)ws_size; (void)n_in; (void)in_sizes; (void)out_size;

    const int NB_N   = (N_NODES + 255) / 256;   // 196
    const int NB_E   = (N_EDGES + 255) / 256;   // 3125
    const int NB_2N  = (N_NODES + 1) / 2;       // 25000 (2 nodes/block)

    // CSR build (runs fresh every call; ws is re-poisoned each timed launch)
    k_zero<<<NB_N, 256, 0, stream>>>(cnt, cursor);
    k_count<<<NB_E, 256, 0, stream>>>(dst, cnt);
    k_dinv<<<NB_N, 256, 0, stream>>>(cnt, dinv);
    k_scan1<<<NB_N, 256, 0, stream>>>(cnt, rowptr, bsum);
    k_scan2<<<1, 256, 0, stream>>>(bsum, NB_N);
    k_scan3<<<NB_N, 256, 0, stream>>>(rowptr, bsum);
    k_fill<<<NB_E, 256, 0, stream>>>(src, dst, rowptr, cursor, csr_src);

    // encoder + 3-layer MLP (relu on first two)
    k_encode<<<NB_2N, 256, 0, stream>>>(x, emb, hA);
    k_mlp<1><<<512, 256, 0, stream>>>(hA, hB, Ws + 0 * EMB * EMB, bs + 0 * EMB);
    k_mlp<1><<<512, 256, 0, stream>>>(hB, hA, Ws + 1 * EMB * EMB, bs + 1 * EMB);
    k_mlp<0><<<512, 256, 0, stream>>>(hA, h0, Ws + 2 * EMB * EMB, bs + 2 * EMB);

    // 10 propagation iterations, double-buffered; last writes d_out
    const float* cur = h0;
    for (int i = 0; i < NITER; ++i) {
        float* dst_buf = (i == NITER - 1) ? out : ((i & 1) ? hB : hA);
        k_prop<<<NB_2N, 256, 0, stream>>>(cur, h0, dst_buf, rowptr, cnt, csr_src, dinv);
        cur = dst_buf;
    }
}

// Round 3
// 905.058 us; speedup vs baseline: 2.1386x; 2.1386x over previous
//
#include <hip/hip_runtime.h>

#define N_NODES 50000
#define N_EDGES 800000
#define EMB 128
#define NFEAT 9
#define VOCAB 119
#define NITER 10
#define ALPHA 0.1f

// ---------------- CSR build ----------------

__global__ void k_zero(int* __restrict__ cnt, int* __restrict__ cursor) {
    int i = blockIdx.x * blockDim.x + threadIdx.x;
    if (i < N_NODES) { cnt[i] = 0; cursor[i] = 0; }
}

__global__ void k_count(const int* __restrict__ dst, int* __restrict__ cnt) {
    int e = blockIdx.x * blockDim.x + threadIdx.x;
    if (e < N_EDGES) atomicAdd(&cnt[dst[e]], 1);
}

__global__ void k_dinv(const int* __restrict__ cnt, float* __restrict__ dinv) {
    int v = blockIdx.x * blockDim.x + threadIdx.x;
    if (v < N_NODES) dinv[v] = rsqrtf((float)(cnt[v] + 1));  // +1 self loop
}

// Exclusive scan of cnt -> rowptr (3-kernel hierarchical scan, 256/block)
__global__ void k_scan1(const int* __restrict__ cnt, int* __restrict__ rowptr,
                        int* __restrict__ bsum) {
    __shared__ int s[256];
    int t = threadIdx.x;
    int idx = blockIdx.x * 256 + t;
    int v = (idx < N_NODES) ? cnt[idx] : 0;
    s[t] = v; __syncthreads();
    for (int off = 1; off < 256; off <<= 1) {
        int add = (t >= off) ? s[t - off] : 0;
        __syncthreads();
        s[t] += add;
        __syncthreads();
    }
    if (idx < N_NODES) rowptr[idx] = s[t] - v;   // exclusive
    if (t == 255) bsum[blockIdx.x] = s[255];     // block total
}

__global__ void k_scan2(int* __restrict__ bsum, int nb) {
    __shared__ int s[256];
    int t = threadIdx.x;
    int v = (t < nb) ? bsum[t] : 0;
    s[t] = v; __syncthreads();
    for (int off = 1; off < 256; off <<= 1) {
        int add = (t >= off) ? s[t - off] : 0;
        __syncthreads();
        s[t] += add;
        __syncthreads();
    }
    if (t < nb) bsum[t] = s[t] - v;              // exclusive block offsets
}

__global__ void k_scan3(int* __restrict__ rowptr, const int* __restrict__ bsum) {
    int idx = blockIdx.x * 256 + threadIdx.x;
    if (idx < N_NODES) rowptr[idx] += bsum[blockIdx.x];
}

__global__ void k_fill(const int* __restrict__ src, const int* __restrict__ dst,
                       const int* __restrict__ rowptr, int* __restrict__ cursor,
                       int* __restrict__ csr_src) {
    int e = blockIdx.x * blockDim.x + threadIdx.x;
    if (e < N_EDGES) {
        int v = dst[e];
        int pos = rowptr[v] + atomicAdd(&cursor[v], 1);
        csr_src[pos] = src[e];
    }
}

// ---------------- encoder ----------------

// 2 nodes per 256-thread block: thread = (sub, d)
__global__ void k_encode(const int* __restrict__ x, const float* __restrict__ emb,
                         float* __restrict__ out) {
    int t = threadIdx.x;
    int d = t & 127, sub = t >> 7;
    int n = blockIdx.x * 2 + sub;
    if (n >= N_NODES) return;
    const int* xr = x + n * NFEAT;
    float s = 0.f;
#pragma unroll
    for (int f = 0; f < NFEAT; ++f) {
        int id = xr[f];
        s += emb[(f * VOCAB + id) * EMB + d];
    }
    out[n * EMB + d] = s;
}

// ---------------- MLP: register-tiled, 32 nodes/block ----------------

__device__ inline void fma4(float4& acc, float4 a, float4 w0, float4 w1,
                            float4 w2, float4 w3) {
    acc.x = fmaf(a.x, w0.x, fmaf(a.y, w1.x, fmaf(a.z, w2.x, fmaf(a.w, w3.x, acc.x))));
    acc.y = fmaf(a.x, w0.y, fmaf(a.y, w1.y, fmaf(a.z, w2.y, fmaf(a.w, w3.y, acc.y))));
    acc.z = fmaf(a.x, w0.z, fmaf(a.y, w1.z, fmaf(a.z, w2.z, fmaf(a.w, w3.z, acc.z))));
    acc.w = fmaf(a.x, w0.w, fmaf(a.y, w1.w, fmaf(a.z, w2.w, fmaf(a.w, w3.w, acc.w))));
}

template <int RELU>
__global__ __launch_bounds__(256) void k_mlp(const float* __restrict__ in,
                                             float* __restrict__ out,
                                             const float* __restrict__ W,
                                             const float* __restrict__ b) {
    __shared__ float4 Wl[EMB * 32];   // 64 KB: Wl[k*32+q] = W[k][4q..4q+3]
    __shared__ float4 hs[32 * 32];    // 16 KB: hs[n*32+kq] = h[node n][4kq..4kq+3]
    int t = threadIdx.x;
    const float4* W4 = (const float4*)W;
    for (int i = t; i < EMB * 32; i += 256) Wl[i] = W4[i];
    int base = blockIdx.x * 32;
    const float4* in4 = (const float4*)in;
    for (int i = t; i < 32 * 32; i += 256) {
        int n = base + (i >> 5);
        hs[i] = (n < N_NODES) ? in4[n * 32 + (i & 31)] : make_float4(0.f, 0.f, 0.f, 0.f);
    }
    __syncthreads();
    int q = t & 31;       // output quad: dims 4q..4q+3
    int g = t >> 5;       // group 0..7: nodes base + 4g .. base + 4g+3
    float4 bias = ((const float4*)b)[q];
    float4 acc0 = bias, acc1 = bias, acc2 = bias, acc3 = bias;
    const float4* h0r = &hs[(g * 4 + 0) * 32];
    const float4* h1r = &hs[(g * 4 + 1) * 32];
    const float4* h2r = &hs[(g * 4 + 2) * 32];
    const float4* h3r = &hs[(g * 4 + 3) * 32];
#pragma unroll 2
    for (int k0 = 0; k0 < EMB; k0 += 4) {
        float4 w0 = Wl[(k0 + 0) * 32 + q];
        float4 w1 = Wl[(k0 + 1) * 32 + q];
        float4 w2 = Wl[(k0 + 2) * 32 + q];
        float4 w3 = Wl[(k0 + 3) * 32 + q];
        int kq = k0 >> 2;
        fma4(acc0, h0r[kq], w0, w1, w2, w3);
        fma4(acc1, h1r[kq], w0, w1, w2, w3);
        fma4(acc2, h2r[kq], w0, w1, w2, w3);
        fma4(acc3, h3r[kq], w0, w1, w2, w3);
    }
    if (RELU) {
        acc0.x = fmaxf(acc0.x, 0.f); acc0.y = fmaxf(acc0.y, 0.f);
        acc0.z = fmaxf(acc0.z, 0.f); acc0.w = fmaxf(acc0.w, 0.f);
        acc1.x = fmaxf(acc1.x, 0.f); acc1.y = fmaxf(acc1.y, 0.f);
        acc1.z = fmaxf(acc1.z, 0.f); acc1.w = fmaxf(acc1.w, 0.f);
        acc2.x = fmaxf(acc2.x, 0.f); acc2.y = fmaxf(acc2.y, 0.f);
        acc2.z = fmaxf(acc2.z, 0.f); acc2.w = fmaxf(acc2.w, 0.f);
        acc3.x = fmaxf(acc3.x, 0.f); acc3.y = fmaxf(acc3.y, 0.f);
        acc3.w = fmaxf(acc3.w, 0.f); acc3.z = fmaxf(acc3.z, 0.f);
    }
    float4* out4 = (float4*)out;
    int n0 = base + g * 4;
    if (n0 + 0 < N_NODES) out4[(n0 + 0) * 32 + q] = acc0;
    if (n0 + 1 < N_NODES) out4[(n0 + 1) * 32 + q] = acc1;
    if (n0 + 2 < N_NODES) out4[(n0 + 2) * 32 + q] = acc2;
    if (n0 + 3 < N_NODES) out4[(n0 + 3) * 32 + q] = acc3;
}

// ---------------- propagation: 1 wave per node, float2, 4x unroll ----------------

__global__ __launch_bounds__(256) void k_prop(const float* __restrict__ hin,
                                              const float* __restrict__ h0,
                                              float* __restrict__ hout,
                                              const int* __restrict__ rowptr,
                                              const int* __restrict__ cnt,
                                              const int* __restrict__ csr_src,
                                              const float* __restrict__ dinv) {
    int t = threadIdx.x;
    int lane = t & 63;                 // float2 column 0..63
    int v = blockIdx.x * 4 + (t >> 6); // 12500 * 4 == 50000 exactly
    int start = rowptr[v];
    int c = cnt[v];
    const float2* hin2 = (const float2*)hin;
    const int* cs = csr_src + start;
    float ax = 0.f, ay = 0.f;
    int i = 0;
    for (; i + 4 <= c; i += 4) {
        int s0 = cs[i], s1 = cs[i + 1], s2 = cs[i + 2], s3 = cs[i + 3];
        float2 g0 = hin2[s0 * 64 + lane];
        float2 g1 = hin2[s1 * 64 + lane];
        float2 g2 = hin2[s2 * 64 + lane];
        float2 g3 = hin2[s3 * 64 + lane];
        float d0 = dinv[s0], d1 = dinv[s1], d2 = dinv[s2], d3 = dinv[s3];
        ax += d0 * g0.x + d1 * g1.x + d2 * g2.x + d3 * g3.x;
        ay += d0 * g0.y + d1 * g1.y + d2 * g2.y + d3 * g3.y;
    }
    for (; i < c; ++i) {
        int s = cs[i];
        float2 g = hin2[s * 64 + lane];
        float d = dinv[s];
        ax += d * g.x;
        ay += d * g.y;
    }
    float dv = dinv[v];
    float2 hv = hin2[v * 64 + lane];
    float2 h0v = ((const float2*)h0)[v * 64 + lane];
    float2 o;
    o.x = (1.f - ALPHA) * (dv * ax + dv * dv * hv.x) + ALPHA * h0v.x;
    o.y = (1.f - ALPHA) * (dv * ay + dv * dv * hv.y) + ALPHA * h0v.y;
    ((float2*)hout)[v * 64 + lane] = o;
}

// ---------------- host ----------------

extern "C" void kernel_launch(void* const* d_in, const int* in_sizes, int n_in,
                              void* d_out, int out_size, void* d_ws, size_t ws_size,
                              hipStream_t stream) {
    const int*   x    = (const int*)d_in[0];             // [N, 9]
    const int*   ei   = (const int*)d_in[1];             // [2, E]
    const float* emb  = (const float*)d_in[2];           // [9, 119, 128]
    const float* Ws   = (const float*)d_in[3];           // [3, 128, 128]
    const float* bs   = (const float*)d_in[4];           // [3, 128]
    float* out = (float*)d_out;                          // [N, 128] f32

    const int* src = ei;
    const int* dst = ei + N_EDGES;

    // workspace carve-up (all 4-byte elems)
    char* w = (char*)d_ws;
    size_t off = 0;
    auto alloc = [&](size_t elems) { void* p = w + off; off += elems * 4; return p; };
    float* h0      = (float*)alloc((size_t)N_NODES * EMB);
    float* hA      = (float*)alloc((size_t)N_NODES * EMB);
    float* hB      = (float*)alloc((size_t)N_NODES * EMB);
    float* dinv    = (float*)alloc(N_NODES);
    int*   cnt     = (int*)alloc(N_NODES);
    int*   cursor  = (int*)alloc(N_NODES);
    int*   rowptr  = (int*)alloc(N_NODES);
    int*   bsum    = (int*)alloc(256);
    int*   csr_src = (int*)alloc(N_EDGES);
    (void)ws_size; (void)n_in; (void)in_sizes; (void)out_size;

    const int NB_N  = (N_NODES + 255) / 256;   // 196
    const int NB_E  = (N_EDGES + 255) / 256;   // 3125
    const int NB_2N = (N_NODES + 1) / 2;       // 25000 (encode: 2 nodes/block)
    const int NB_M  = (N_NODES + 31) / 32;     // 1563 (mlp: 32 nodes/block)
    const int NB_P  = N_NODES / 4;             // 12500 (prop: 4 nodes/block, exact)

    // CSR build (runs fresh every call; ws is re-poisoned each timed launch)
    k_zero<<<NB_N, 256, 0, stream>>>(cnt, cursor);
    k_count<<<NB_E, 256, 0, stream>>>(dst, cnt);
    k_dinv<<<NB_N, 256, 0, stream>>>(cnt, dinv);
    k_scan1<<<NB_N, 256, 0, stream>>>(cnt, rowptr, bsum);
    k_scan2<<<1, 256, 0, stream>>>(bsum, NB_N);
    k_scan3<<<NB_N, 256, 0, stream>>>(rowptr, bsum);
    k_fill<<<NB_E, 256, 0, stream>>>(src, dst, rowptr, cursor, csr_src);

    // encoder + 3-layer MLP (relu on first two)
    k_encode<<<NB_2N, 256, 0, stream>>>(x, emb, hA);
    k_mlp<1><<<NB_M, 256, 0, stream>>>(hA, hB, Ws + 0 * EMB * EMB, bs + 0 * EMB);
    k_mlp<1><<<NB_M, 256, 0, stream>>>(hB, hA, Ws + 1 * EMB * EMB, bs + 1 * EMB);
    k_mlp<0><<<NB_M, 256, 0, stream>>>(hA, h0, Ws + 2 * EMB * EMB, bs + 2 * EMB);

    // 10 propagation iterations, double-buffered; last writes d_out
    const float* cur = h0;
    for (int i = 0; i < NITER; ++i) {
        float* dst_buf = (i == NITER - 1) ? out : ((i & 1) ? hB : hA);
        k_prop<<<NB_P, 256, 0, stream>>>(cur, h0, dst_buf, rowptr, cnt, csr_src, dinv);
        cur = dst_buf;
    }
}

// Round 4
// 887.976 us; speedup vs baseline: 2.1797x; 1.0192x over previous
//
#include <hip/hip_runtime.h>

#define N_NODES 50000
#define N_EDGES 800000
#define EMB 128
#define NFEAT 9
#define VOCAB 119
#define NITER 10
#define ALPHA 0.1f

// ---------------- CSR build ----------------

__global__ void k_zero(int* __restrict__ cnt, int* __restrict__ cursor) {
    int i = blockIdx.x * blockDim.x + threadIdx.x;
    if (i < N_NODES) { cnt[i] = 0; cursor[i] = 0; }
}

__global__ void k_count(const int* __restrict__ dst, int* __restrict__ cnt) {
    int e = blockIdx.x * blockDim.x + threadIdx.x;
    if (e < N_EDGES) atomicAdd(&cnt[dst[e]], 1);
}

__global__ void k_dinv(const int* __restrict__ cnt, float* __restrict__ dinv) {
    int v = blockIdx.x * blockDim.x + threadIdx.x;
    if (v < N_NODES) dinv[v] = rsqrtf((float)(cnt[v] + 1));  // +1 self loop
}

// Exclusive scan of cnt -> rowptr (3-kernel hierarchical scan, 256/block)
__global__ void k_scan1(const int* __restrict__ cnt, int* __restrict__ rowptr,
                        int* __restrict__ bsum) {
    __shared__ int s[256];
    int t = threadIdx.x;
    int idx = blockIdx.x * 256 + t;
    int v = (idx < N_NODES) ? cnt[idx] : 0;
    s[t] = v; __syncthreads();
    for (int off = 1; off < 256; off <<= 1) {
        int add = (t >= off) ? s[t - off] : 0;
        __syncthreads();
        s[t] += add;
        __syncthreads();
    }
    if (idx < N_NODES) rowptr[idx] = s[t] - v;   // exclusive
    if (t == 255) bsum[blockIdx.x] = s[255];     // block total
}

__global__ void k_scan2(int* __restrict__ bsum, int nb) {
    __shared__ int s[256];
    int t = threadIdx.x;
    int v = (t < nb) ? bsum[t] : 0;
    s[t] = v; __syncthreads();
    for (int off = 1; off < 256; off <<= 1) {
        int add = (t >= off) ? s[t - off] : 0;
        __syncthreads();
        s[t] += add;
        __syncthreads();
    }
    if (t < nb) bsum[t] = s[t] - v;              // exclusive block offsets
}

__global__ void k_scan3(int* __restrict__ rowptr, const int* __restrict__ bsum) {
    int idx = blockIdx.x * 256 + threadIdx.x;
    if (idx < N_NODES) rowptr[idx] += bsum[blockIdx.x];
}

__global__ void k_fill(const int* __restrict__ src, const int* __restrict__ dst,
                       const int* __restrict__ rowptr, int* __restrict__ cursor,
                       int* __restrict__ csr_src) {
    int e = blockIdx.x * blockDim.x + threadIdx.x;
    if (e < N_EDGES) {
        int v = dst[e];
        int pos = rowptr[v] + atomicAdd(&cursor[v], 1);
        csr_src[pos] = src[e];
    }
}

// ---------------- encoder ----------------

// 2 nodes per 256-thread block: thread = (sub, d)
__global__ void k_encode(const int* __restrict__ x, const float* __restrict__ emb,
                         float* __restrict__ out) {
    int t = threadIdx.x;
    int d = t & 127, sub = t >> 7;
    int n = blockIdx.x * 2 + sub;
    if (n >= N_NODES) return;
    const int* xr = x + n * NFEAT;
    float s = 0.f;
#pragma unroll
    for (int f = 0; f < NFEAT; ++f) {
        int id = xr[f];
        s += emb[(f * VOCAB + id) * EMB + d];
    }
    out[n * EMB + d] = s;
}

// ---------------- MLP: register-tiled, 32 nodes/block ----------------

__device__ inline void fma4(float4& acc, float4 a, float4 w0, float4 w1,
                            float4 w2, float4 w3) {
    acc.x = fmaf(a.x, w0.x, fmaf(a.y, w1.x, fmaf(a.z, w2.x, fmaf(a.w, w3.x, acc.x))));
    acc.y = fmaf(a.x, w0.y, fmaf(a.y, w1.y, fmaf(a.z, w2.y, fmaf(a.w, w3.y, acc.y))));
    acc.z = fmaf(a.x, w0.z, fmaf(a.y, w1.z, fmaf(a.z, w2.z, fmaf(a.w, w3.z, acc.z))));
    acc.w = fmaf(a.x, w0.w, fmaf(a.y, w1.w, fmaf(a.z, w2.w, fmaf(a.w, w3.w, acc.w))));
}

__device__ inline float4 relu4(float4 a) {
    return make_float4(fmaxf(a.x, 0.f), fmaxf(a.y, 0.f), fmaxf(a.z, 0.f), fmaxf(a.w, 0.f));
}

__device__ inline float4 scale4(float4 a, float s) {
    return make_float4(a.x * s, a.y * s, a.z * s, a.w * s);
}

// WQ: also write q0 = dinv * h (fused prescale for propagation)
template <int RELU, int WQ>
__global__ __launch_bounds__(256) void k_mlp(const float* __restrict__ in,
                                             float* __restrict__ out,
                                             const float* __restrict__ W,
                                             const float* __restrict__ b,
                                             const float* __restrict__ dinv,
                                             float4* __restrict__ q0out) {
    __shared__ float4 Wl[EMB * 32];   // 64 KB: Wl[k*32+q] = W[k][4q..4q+3]
    __shared__ float4 hs[32 * 32];    // 16 KB: hs[n*32+kq] = h[node n][4kq..4kq+3]
    int t = threadIdx.x;
    const float4* W4 = (const float4*)W;
    for (int i = t; i < EMB * 32; i += 256) Wl[i] = W4[i];
    int base = blockIdx.x * 32;
    const float4* in4 = (const float4*)in;
    for (int i = t; i < 32 * 32; i += 256) {
        int n = base + (i >> 5);
        hs[i] = (n < N_NODES) ? in4[n * 32 + (i & 31)] : make_float4(0.f, 0.f, 0.f, 0.f);
    }
    __syncthreads();
    int q = t & 31;       // output quad: dims 4q..4q+3
    int g = t >> 5;       // group 0..7: nodes base + 4g .. base + 4g+3
    float4 bias = ((const float4*)b)[q];
    float4 acc0 = bias, acc1 = bias, acc2 = bias, acc3 = bias;
    const float4* h0r = &hs[(g * 4 + 0) * 32];
    const float4* h1r = &hs[(g * 4 + 1) * 32];
    const float4* h2r = &hs[(g * 4 + 2) * 32];
    const float4* h3r = &hs[(g * 4 + 3) * 32];
#pragma unroll 2
    for (int k0 = 0; k0 < EMB; k0 += 4) {
        float4 w0 = Wl[(k0 + 0) * 32 + q];
        float4 w1 = Wl[(k0 + 1) * 32 + q];
        float4 w2 = Wl[(k0 + 2) * 32 + q];
        float4 w3 = Wl[(k0 + 3) * 32 + q];
        int kq = k0 >> 2;
        fma4(acc0, h0r[kq], w0, w1, w2, w3);
        fma4(acc1, h1r[kq], w0, w1, w2, w3);
        fma4(acc2, h2r[kq], w0, w1, w2, w3);
        fma4(acc3, h3r[kq], w0, w1, w2, w3);
    }
    if (RELU) {
        acc0 = relu4(acc0); acc1 = relu4(acc1);
        acc2 = relu4(acc2); acc3 = relu4(acc3);
    }
    float4* out4 = (float4*)out;
    int n0 = base + g * 4;
    if (n0 + 0 < N_NODES) out4[(n0 + 0) * 32 + q] = acc0;
    if (n0 + 1 < N_NODES) out4[(n0 + 1) * 32 + q] = acc1;
    if (n0 + 2 < N_NODES) out4[(n0 + 2) * 32 + q] = acc2;
    if (n0 + 3 < N_NODES) out4[(n0 + 3) * 32 + q] = acc3;
    if (WQ) {
        if (n0 + 0 < N_NODES) q0out[(n0 + 0) * 32 + q] = scale4(acc0, dinv[n0 + 0]);
        if (n0 + 1 < N_NODES) q0out[(n0 + 1) * 32 + q] = scale4(acc1, dinv[n0 + 1]);
        if (n0 + 2 < N_NODES) q0out[(n0 + 2) * 32 + q] = scale4(acc2, dinv[n0 + 2]);
        if (n0 + 3 < N_NODES) q0out[(n0 + 3) * 32 + q] = scale4(acc3, dinv[n0 + 3]);
    }
}

// ---------------- propagation on q = dinv*h ----------------
// wave per node; lane = (half, dq): half h reads edges of parity h as float4
// rows -> one global_load_dwordx4 covers TWO 512B rows (1024B). Halves are
// combined with shfl_xor(32). Inner loop is pure `acc += q[s]` (dinv folded
// into q). Recurrence: h' = 0.9*dinv*(sum + q[v]) + 0.1*h0 ; q' = dinv*h'.

template <int LAST>
__global__ __launch_bounds__(256) void k_prop(const float4* __restrict__ qin,
                                              const float4* __restrict__ h0,
                                              float4* __restrict__ outb,  // q' or h'
                                              const int* __restrict__ rowptr,
                                              const int* __restrict__ cnt,
                                              const int* __restrict__ csr_src,
                                              const float* __restrict__ dinv) {
    int t = threadIdx.x;
    int lane = t & 63;
    int half = lane >> 5;              // edge parity this half handles
    int dq = lane & 31;                // float4 quad: dims 4dq..4dq+3
    int v = blockIdx.x * 4 + (t >> 6); // 12500 * 4 == 50000 exactly
    int start = rowptr[v];
    int c = cnt[v];
    const int* cs = csr_src + start;
    float4 acc = make_float4(0.f, 0.f, 0.f, 0.f);
    int i = 0;
    for (; i + 8 <= c; i += 8) {
        int s0 = cs[i + 0 + half];
        int s1 = cs[i + 2 + half];
        int s2 = cs[i + 4 + half];
        int s3 = cs[i + 6 + half];
        float4 g0 = qin[s0 * 32 + dq];
        float4 g1 = qin[s1 * 32 + dq];
        float4 g2 = qin[s2 * 32 + dq];
        float4 g3 = qin[s3 * 32 + dq];
        acc.x += (g0.x + g1.x) + (g2.x + g3.x);
        acc.y += (g0.y + g1.y) + (g2.y + g3.y);
        acc.z += (g0.z + g1.z) + (g2.z + g3.z);
        acc.w += (g0.w + g1.w) + (g2.w + g3.w);
    }
    for (; i < c; i += 2) {
        int e = i + half;
        if (e < c) {
            float4 g = qin[cs[e] * 32 + dq];
            acc.x += g.x; acc.y += g.y; acc.z += g.z; acc.w += g.w;
        }
    }
    // combine the two halves (each lane ends with the full neighbor sum)
    acc.x += __shfl_xor(acc.x, 32);
    acc.y += __shfl_xor(acc.y, 32);
    acc.z += __shfl_xor(acc.z, 32);
    acc.w += __shfl_xor(acc.w, 32);
    float dv = dinv[v];
    float4 qv = qin[v * 32 + dq];
    float4 h0v = h0[v * 32 + dq];
    float4 h;
    h.x = (1.f - ALPHA) * dv * (acc.x + qv.x) + ALPHA * h0v.x;
    h.y = (1.f - ALPHA) * dv * (acc.y + qv.y) + ALPHA * h0v.y;
    h.z = (1.f - ALPHA) * dv * (acc.z + qv.z) + ALPHA * h0v.z;
    h.w = (1.f - ALPHA) * dv * (acc.w + qv.w) + ALPHA * h0v.w;
    if (half == 0) {
        outb[v * 32 + dq] = LAST ? h : scale4(h, dv);
    }
}

// ---------------- host ----------------

extern "C" void kernel_launch(void* const* d_in, const int* in_sizes, int n_in,
                              void* d_out, int out_size, void* d_ws, size_t ws_size,
                              hipStream_t stream) {
    const int*   x    = (const int*)d_in[0];             // [N, 9]
    const int*   ei   = (const int*)d_in[1];             // [2, E]
    const float* emb  = (const float*)d_in[2];           // [9, 119, 128]
    const float* Ws   = (const float*)d_in[3];           // [3, 128, 128]
    const float* bs   = (const float*)d_in[4];           // [3, 128]
    float* out = (float*)d_out;                          // [N, 128] f32

    const int* src = ei;
    const int* dst = ei + N_EDGES;

    // workspace carve-up (all 4-byte elems)
    char* w = (char*)d_ws;
    size_t off = 0;
    auto alloc = [&](size_t elems) { void* p = w + off; off += elems * 4; return p; };
    float* h0      = (float*)alloc((size_t)N_NODES * EMB);
    float* qA      = (float*)alloc((size_t)N_NODES * EMB);
    float* qB      = (float*)alloc((size_t)N_NODES * EMB);
    float* hT      = (float*)alloc((size_t)N_NODES * EMB);  // MLP temp
    float* dinv    = (float*)alloc(N_NODES);
    int*   cnt     = (int*)alloc(N_NODES);
    int*   cursor  = (int*)alloc(N_NODES);
    int*   rowptr  = (int*)alloc(N_NODES);
    int*   bsum    = (int*)alloc(256);
    int*   csr_src = (int*)alloc(N_EDGES);
    (void)ws_size; (void)n_in; (void)in_sizes; (void)out_size;

    const int NB_N  = (N_NODES + 255) / 256;   // 196
    const int NB_E  = (N_EDGES + 255) / 256;   // 3125
    const int NB_2N = (N_NODES + 1) / 2;       // 25000 (encode: 2 nodes/block)
    const int NB_M  = (N_NODES + 31) / 32;     // 1563 (mlp: 32 nodes/block)
    const int NB_P  = N_NODES / 4;             // 12500 (prop: 4 nodes/block, exact)

    // CSR build (runs fresh every call; ws is re-poisoned each timed launch)
    k_zero<<<NB_N, 256, 0, stream>>>(cnt, cursor);
    k_count<<<NB_E, 256, 0, stream>>>(dst, cnt);
    k_dinv<<<NB_N, 256, 0, stream>>>(cnt, dinv);
    k_scan1<<<NB_N, 256, 0, stream>>>(cnt, rowptr, bsum);
    k_scan2<<<1, 256, 0, stream>>>(bsum, NB_N);
    k_scan3<<<NB_N, 256, 0, stream>>>(rowptr, bsum);
    k_fill<<<NB_E, 256, 0, stream>>>(src, dst, rowptr, cursor, csr_src);

    // encoder + 3-layer MLP (relu on first two); last layer also writes q0
    k_encode<<<NB_2N, 256, 0, stream>>>(x, emb, hT);
    k_mlp<1, 0><<<NB_M, 256, 0, stream>>>(hT, qB, Ws + 0 * EMB * EMB, bs + 0 * EMB,
                                          nullptr, nullptr);
    k_mlp<1, 0><<<NB_M, 256, 0, stream>>>(qB, hT, Ws + 1 * EMB * EMB, bs + 1 * EMB,
                                          nullptr, nullptr);
    k_mlp<0, 1><<<NB_M, 256, 0, stream>>>(hT, h0, Ws + 2 * EMB * EMB, bs + 2 * EMB,
                                          dinv, (float4*)qA);

    // 10 propagation iterations on q, double-buffered; last writes h to d_out
    const float4* qin = (const float4*)qA;
    for (int i = 0; i < NITER; ++i) {
        if (i == NITER - 1) {
            k_prop<1><<<NB_P, 256, 0, stream>>>(qin, (const float4*)h0, (float4*)out,
                                                rowptr, cnt, csr_src, dinv);
        } else {
            float4* qo = (float4*)((i & 1) ? qA : qB);
            k_prop<0><<<NB_P, 256, 0, stream>>>(qin, (const float4*)h0, qo,
                                                rowptr, cnt, csr_src, dinv);
            qin = qo;
        }
    }
}

// Round 5
// 643.681 us; speedup vs baseline: 3.0070x; 1.3795x over previous
//
#include <hip/hip_runtime.h>

#define N_NODES 50000
#define N_EDGES 800000
#define EMB 128
#define NFEAT 9
#define VOCAB 119
#define NITER 10
#define ALPHA 0.1f

// ---------------- bf16 helpers (manual RNE, no lib dependency) ----------------

__device__ inline unsigned int f2bf1(float x) {
    union { float f; unsigned u; } v; v.f = x;
    unsigned r = v.u + 0x7fffu + ((v.u >> 16) & 1u);
    return r >> 16;
}
__device__ inline unsigned int f2bf2(float lo, float hi) {
    return f2bf1(lo) | (f2bf1(hi) << 16);
}
__device__ inline float bf2f_lo(unsigned u) {
    union { unsigned u; float f; } v; v.u = u << 16; return v.f;
}
__device__ inline float bf2f_hi(unsigned u) {
    union { unsigned u; float f; } v; v.u = u & 0xffff0000u; return v.f;
}

// ---------------- CSR build ----------------

__global__ void k_zero(int* __restrict__ cnt, int* __restrict__ cursor) {
    int i = blockIdx.x * blockDim.x + threadIdx.x;
    if (i < N_NODES) { cnt[i] = 0; cursor[i] = 0; }
}

__global__ void k_count(const int* __restrict__ dst, int* __restrict__ cnt) {
    int e = blockIdx.x * blockDim.x + threadIdx.x;
    if (e < N_EDGES) atomicAdd(&cnt[dst[e]], 1);
}

__global__ void k_dinv(const int* __restrict__ cnt, float* __restrict__ dinv) {
    int v = blockIdx.x * blockDim.x + threadIdx.x;
    if (v < N_NODES) dinv[v] = rsqrtf((float)(cnt[v] + 1));  // +1 self loop
}

__global__ void k_scan1(const int* __restrict__ cnt, int* __restrict__ rowptr,
                        int* __restrict__ bsum) {
    __shared__ int s[256];
    int t = threadIdx.x;
    int idx = blockIdx.x * 256 + t;
    int v = (idx < N_NODES) ? cnt[idx] : 0;
    s[t] = v; __syncthreads();
    for (int off = 1; off < 256; off <<= 1) {
        int add = (t >= off) ? s[t - off] : 0;
        __syncthreads();
        s[t] += add;
        __syncthreads();
    }
    if (idx < N_NODES) rowptr[idx] = s[t] - v;   // exclusive
    if (t == 255) bsum[blockIdx.x] = s[255];     // block total
}

__global__ void k_scan2(int* __restrict__ bsum, int nb) {
    __shared__ int s[256];
    int t = threadIdx.x;
    int v = (t < nb) ? bsum[t] : 0;
    s[t] = v; __syncthreads();
    for (int off = 1; off < 256; off <<= 1) {
        int add = (t >= off) ? s[t - off] : 0;
        __syncthreads();
        s[t] += add;
        __syncthreads();
    }
    if (t < nb) bsum[t] = s[t] - v;              // exclusive block offsets
}

__global__ void k_scan3(int* __restrict__ rowptr, const int* __restrict__ bsum) {
    int idx = blockIdx.x * 256 + threadIdx.x;
    if (idx < N_NODES) rowptr[idx] += bsum[blockIdx.x];
}

__global__ void k_fill(const int* __restrict__ src, const int* __restrict__ dst,
                       const int* __restrict__ rowptr, int* __restrict__ cursor,
                       int* __restrict__ csr_src) {
    int e = blockIdx.x * blockDim.x + threadIdx.x;
    if (e < N_EDGES) {
        int v = dst[e];
        int pos = rowptr[v] + atomicAdd(&cursor[v], 1);
        csr_src[pos] = src[e];
    }
}

// ---------------- encoder ----------------

__global__ void k_encode(const int* __restrict__ x, const float* __restrict__ emb,
                         float* __restrict__ out) {
    int t = threadIdx.x;
    int d = t & 127, sub = t >> 7;
    int n = blockIdx.x * 2 + sub;
    if (n >= N_NODES) return;
    const int* xr = x + n * NFEAT;
    float s = 0.f;
#pragma unroll
    for (int f = 0; f < NFEAT; ++f) {
        int id = xr[f];
        s += emb[(f * VOCAB + id) * EMB + d];
    }
    out[n * EMB + d] = s;
}

// ---------------- MLP: register-tiled, 32 nodes/block ----------------

__device__ inline void fma4(float4& acc, float4 a, float4 w0, float4 w1,
                            float4 w2, float4 w3) {
    acc.x = fmaf(a.x, w0.x, fmaf(a.y, w1.x, fmaf(a.z, w2.x, fmaf(a.w, w3.x, acc.x))));
    acc.y = fmaf(a.x, w0.y, fmaf(a.y, w1.y, fmaf(a.z, w2.y, fmaf(a.w, w3.y, acc.y))));
    acc.z = fmaf(a.x, w0.z, fmaf(a.y, w1.z, fmaf(a.z, w2.z, fmaf(a.w, w3.z, acc.z))));
    acc.w = fmaf(a.x, w0.w, fmaf(a.y, w1.w, fmaf(a.z, w2.w, fmaf(a.w, w3.w, acc.w))));
}

__device__ inline float4 relu4(float4 a) {
    return make_float4(fmaxf(a.x, 0.f), fmaxf(a.y, 0.f), fmaxf(a.z, 0.f), fmaxf(a.w, 0.f));
}

// WQ: also write q0 = bf16(dinv * h) (fused prescale for propagation)
template <int RELU, int WQ>
__global__ __launch_bounds__(256) void k_mlp(const float* __restrict__ in,
                                             float* __restrict__ out,
                                             const float* __restrict__ W,
                                             const float* __restrict__ b,
                                             const float* __restrict__ dinv,
                                             uint2* __restrict__ q0out) {
    __shared__ float4 Wl[EMB * 32];   // 64 KB: Wl[k*32+q] = W[k][4q..4q+3]
    __shared__ float4 hs[32 * 32];    // 16 KB: hs[n*32+kq] = h[node n][4kq..4kq+3]
    int t = threadIdx.x;
    const float4* W4 = (const float4*)W;
    for (int i = t; i < EMB * 32; i += 256) Wl[i] = W4[i];
    int base = blockIdx.x * 32;
    const float4* in4 = (const float4*)in;
    for (int i = t; i < 32 * 32; i += 256) {
        int n = base + (i >> 5);
        hs[i] = (n < N_NODES) ? in4[n * 32 + (i & 31)] : make_float4(0.f, 0.f, 0.f, 0.f);
    }
    __syncthreads();
    int q = t & 31;       // output quad: dims 4q..4q+3
    int g = t >> 5;       // group 0..7: nodes base + 4g .. base + 4g+3
    float4 bias = ((const float4*)b)[q];
    float4 acc0 = bias, acc1 = bias, acc2 = bias, acc3 = bias;
    const float4* h0r = &hs[(g * 4 + 0) * 32];
    const float4* h1r = &hs[(g * 4 + 1) * 32];
    const float4* h2r = &hs[(g * 4 + 2) * 32];
    const float4* h3r = &hs[(g * 4 + 3) * 32];
#pragma unroll 2
    for (int k0 = 0; k0 < EMB; k0 += 4) {
        float4 w0 = Wl[(k0 + 0) * 32 + q];
        float4 w1 = Wl[(k0 + 1) * 32 + q];
        float4 w2 = Wl[(k0 + 2) * 32 + q];
        float4 w3 = Wl[(k0 + 3) * 32 + q];
        int kq = k0 >> 2;
        fma4(acc0, h0r[kq], w0, w1, w2, w3);
        fma4(acc1, h1r[kq], w0, w1, w2, w3);
        fma4(acc2, h2r[kq], w0, w1, w2, w3);
        fma4(acc3, h3r[kq], w0, w1, w2, w3);
    }
    if (RELU) {
        acc0 = relu4(acc0); acc1 = relu4(acc1);
        acc2 = relu4(acc2); acc3 = relu4(acc3);
    }
    float4* out4 = (float4*)out;
    int n0 = base + g * 4;
    if (n0 + 0 < N_NODES) out4[(n0 + 0) * 32 + q] = acc0;
    if (n0 + 1 < N_NODES) out4[(n0 + 1) * 32 + q] = acc1;
    if (n0 + 2 < N_NODES) out4[(n0 + 2) * 32 + q] = acc2;
    if (n0 + 3 < N_NODES) out4[(n0 + 3) * 32 + q] = acc3;
    if (WQ) {
        if (n0 + 0 < N_NODES) {
            float s = dinv[n0 + 0];
            q0out[(n0 + 0) * 32 + q] =
                make_uint2(f2bf2(acc0.x * s, acc0.y * s), f2bf2(acc0.z * s, acc0.w * s));
        }
        if (n0 + 1 < N_NODES) {
            float s = dinv[n0 + 1];
            q0out[(n0 + 1) * 32 + q] =
                make_uint2(f2bf2(acc1.x * s, acc1.y * s), f2bf2(acc1.z * s, acc1.w * s));
        }
        if (n0 + 2 < N_NODES) {
            float s = dinv[n0 + 2];
            q0out[(n0 + 2) * 32 + q] =
                make_uint2(f2bf2(acc2.x * s, acc2.y * s), f2bf2(acc2.z * s, acc2.w * s));
        }
        if (n0 + 3 < N_NODES) {
            float s = dinv[n0 + 3];
            q0out[(n0 + 3) * 32 + q] =
                make_uint2(f2bf2(acc3.x * s, acc3.y * s), f2bf2(acc3.z * s, acc3.w * s));
        }
    }
}

// ---------------- propagation on bf16 q = dinv*h ----------------
// Row = 128 bf16 = 256 B = 16 uint4. Wave per node; lane = (pair 0..3, dq 0..15).
// One global_load_dwordx4 per lane covers FOUR rows per wave (1024 B).
// pair p handles edges i+p; halves combined with shfl_xor 16 & 32.
// Recurrence: h' = 0.9*dinv*(sum_q + q[v]) + 0.1*h0 ; q' = bf16(dinv * h').

#define ACC8(g) \
    a0 += bf2f_lo((g).x); a1 += bf2f_hi((g).x); \
    a2 += bf2f_lo((g).y); a3 += bf2f_hi((g).y); \
    a4 += bf2f_lo((g).z); a5 += bf2f_hi((g).z); \
    a6 += bf2f_lo((g).w); a7 += bf2f_hi((g).w);

template <int LAST>
__global__ __launch_bounds__(256) void k_prop(const uint4* __restrict__ qin,
                                              const float4* __restrict__ h0,
                                              void* __restrict__ outb,  // bf16 q' or f32 h'
                                              const int* __restrict__ rowptr,
                                              const int* __restrict__ cnt,
                                              const int* __restrict__ csr_src,
                                              const float* __restrict__ dinv) {
    int t = threadIdx.x;
    int lane = t & 63;
    int pair = lane >> 4;              // 0..3: edge sub-slot
    int dq = lane & 15;                // dims 8dq..8dq+7
    int v = blockIdx.x * 4 + (t >> 6); // 12500 * 4 == 50000 exactly
    int start = rowptr[v];
    int c = cnt[v];
    const int* cs = csr_src + start;
    float a0 = 0.f, a1 = 0.f, a2 = 0.f, a3 = 0.f;
    float a4 = 0.f, a5 = 0.f, a6 = 0.f, a7 = 0.f;
    int i = 0;
    for (; i + 8 <= c; i += 8) {
        int s0 = cs[i + pair];
        int s1 = cs[i + 4 + pair];
        uint4 g0 = qin[s0 * 16 + dq];
        uint4 g1 = qin[s1 * 16 + dq];
        ACC8(g0);
        ACC8(g1);
    }
    for (; i < c; i += 4) {
        int e = i + pair;
        if (e < c) {
            uint4 g = qin[cs[e] * 16 + dq];
            ACC8(g);
        }
    }
    // combine the 4 pair-slots: after this, all lanes hold the full sums
    a0 += __shfl_xor(a0, 16); a0 += __shfl_xor(a0, 32);
    a1 += __shfl_xor(a1, 16); a1 += __shfl_xor(a1, 32);
    a2 += __shfl_xor(a2, 16); a2 += __shfl_xor(a2, 32);
    a3 += __shfl_xor(a3, 16); a3 += __shfl_xor(a3, 32);
    a4 += __shfl_xor(a4, 16); a4 += __shfl_xor(a4, 32);
    a5 += __shfl_xor(a5, 16); a5 += __shfl_xor(a5, 32);
    a6 += __shfl_xor(a6, 16); a6 += __shfl_xor(a6, 32);
    a7 += __shfl_xor(a7, 16); a7 += __shfl_xor(a7, 32);

    float dv = dinv[v];
    uint4 qv = qin[v * 16 + dq];  // self term (quantized q, consistent)
    float4 hlo = h0[v * 32 + 2 * dq];
    float4 hhi = h0[v * 32 + 2 * dq + 1];
    float h_0 = (1.f - ALPHA) * dv * (a0 + bf2f_lo(qv.x)) + ALPHA * hlo.x;
    float h_1 = (1.f - ALPHA) * dv * (a1 + bf2f_hi(qv.x)) + ALPHA * hlo.y;
    float h_2 = (1.f - ALPHA) * dv * (a2 + bf2f_lo(qv.y)) + ALPHA * hlo.z;
    float h_3 = (1.f - ALPHA) * dv * (a3 + bf2f_hi(qv.y)) + ALPHA * hlo.w;
    float h_4 = (1.f - ALPHA) * dv * (a4 + bf2f_lo(qv.z)) + ALPHA * hhi.x;
    float h_5 = (1.f - ALPHA) * dv * (a5 + bf2f_hi(qv.z)) + ALPHA * hhi.y;
    float h_6 = (1.f - ALPHA) * dv * (a6 + bf2f_lo(qv.w)) + ALPHA * hhi.z;
    float h_7 = (1.f - ALPHA) * dv * (a7 + bf2f_hi(qv.w)) + ALPHA * hhi.w;

    if (LAST) {
        // f32 output: 32 lanes (pair 0,1) each store one float4
        if (pair < 2) {
            float4 wv = (pair == 0) ? make_float4(h_0, h_1, h_2, h_3)
                                    : make_float4(h_4, h_5, h_6, h_7);
            ((float4*)outb)[v * 32 + 2 * dq + pair] = wv;
        }
    } else {
        // bf16 q' output: 16 lanes (pair 0) each store one uint4 (8 bf16)
        if (pair == 0) {
            uint4 wv;
            wv.x = f2bf2(h_0 * dv, h_1 * dv);
            wv.y = f2bf2(h_2 * dv, h_3 * dv);
            wv.z = f2bf2(h_4 * dv, h_5 * dv);
            wv.w = f2bf2(h_6 * dv, h_7 * dv);
            ((uint4*)outb)[v * 16 + dq] = wv;
        }
    }
}

// ---------------- host ----------------

extern "C" void kernel_launch(void* const* d_in, const int* in_sizes, int n_in,
                              void* d_out, int out_size, void* d_ws, size_t ws_size,
                              hipStream_t stream) {
    const int*   x    = (const int*)d_in[0];             // [N, 9]
    const int*   ei   = (const int*)d_in[1];             // [2, E]
    const float* emb  = (const float*)d_in[2];           // [9, 119, 128]
    const float* Ws   = (const float*)d_in[3];           // [3, 128, 128]
    const float* bs   = (const float*)d_in[4];           // [3, 128]
    float* out = (float*)d_out;                          // [N, 128] f32

    const int* src = ei;
    const int* dst = ei + N_EDGES;

    // workspace carve-up (byte-based)
    char* w = (char*)d_ws;
    size_t off = 0;
    auto alloc = [&](size_t bytes) {
        void* p = w + off;
        off += (bytes + 255) & ~(size_t)255;  // keep 256B alignment
        return p;
    };
    float* h0      = (float*)alloc((size_t)N_NODES * EMB * 4);
    float* hT      = (float*)alloc((size_t)N_NODES * EMB * 4);
    float* hU      = (float*)alloc((size_t)N_NODES * EMB * 4);
    void*  qA      = alloc((size_t)N_NODES * EMB * 2);   // bf16
    void*  qB      = alloc((size_t)N_NODES * EMB * 2);   // bf16
    float* dinv    = (float*)alloc(N_NODES * 4);
    int*   cnt     = (int*)alloc(N_NODES * 4);
    int*   cursor  = (int*)alloc(N_NODES * 4);
    int*   rowptr  = (int*)alloc(N_NODES * 4);
    int*   bsum    = (int*)alloc(256 * 4);
    int*   csr_src = (int*)alloc(N_EDGES * 4);
    (void)ws_size; (void)n_in; (void)in_sizes; (void)out_size;

    const int NB_N  = (N_NODES + 255) / 256;   // 196
    const int NB_E  = (N_EDGES + 255) / 256;   // 3125
    const int NB_2N = (N_NODES + 1) / 2;       // 25000 (encode: 2 nodes/block)
    const int NB_M  = (N_NODES + 31) / 32;     // 1563 (mlp: 32 nodes/block)
    const int NB_P  = N_NODES / 4;             // 12500 (prop: 4 nodes/block, exact)

    // CSR build (runs fresh every call; ws is re-poisoned each timed launch)
    k_zero<<<NB_N, 256, 0, stream>>>(cnt, cursor);
    k_count<<<NB_E, 256, 0, stream>>>(dst, cnt);
    k_dinv<<<NB_N, 256, 0, stream>>>(cnt, dinv);
    k_scan1<<<NB_N, 256, 0, stream>>>(cnt, rowptr, bsum);
    k_scan2<<<1, 256, 0, stream>>>(bsum, NB_N);
    k_scan3<<<NB_N, 256, 0, stream>>>(rowptr, bsum);
    k_fill<<<NB_E, 256, 0, stream>>>(src, dst, rowptr, cursor, csr_src);

    // encoder + 3-layer MLP (relu on first two); last layer also writes bf16 q0
    k_encode<<<NB_2N, 256, 0, stream>>>(x, emb, hT);
    k_mlp<1, 0><<<NB_M, 256, 0, stream>>>(hT, hU, Ws + 0 * EMB * EMB, bs + 0 * EMB,
                                          nullptr, nullptr);
    k_mlp<1, 0><<<NB_M, 256, 0, stream>>>(hU, hT, Ws + 1 * EMB * EMB, bs + 1 * EMB,
                                          nullptr, nullptr);
    k_mlp<0, 1><<<NB_M, 256, 0, stream>>>(hT, h0, Ws + 2 * EMB * EMB, bs + 2 * EMB,
                                          dinv, (uint2*)qA);

    // 10 propagation iterations on bf16 q, double-buffered; last writes f32 h to d_out
    const uint4* qin = (const uint4*)qA;
    for (int i = 0; i < NITER; ++i) {
        if (i == NITER - 1) {
            k_prop<1><<<NB_P, 256, 0, stream>>>(qin, (const float4*)h0, out,
                                                rowptr, cnt, csr_src, dinv);
        } else {
            void* qo = (i & 1) ? qA : qB;
            k_prop<0><<<NB_P, 256, 0, stream>>>(qin, (const float4*)h0, qo,
                                                rowptr, cnt, csr_src, dinv);
            qin = (const uint4*)qo;
        }
    }
}

// Round 6
// 589.700 us; speedup vs baseline: 3.2823x; 1.0915x over previous
//
#include <hip/hip_runtime.h>

#define N_NODES 50000
#define N_EDGES 800000
#define EMB 128
#define NFEAT 9
#define VOCAB 119
#define NITER 10
#define ALPHA 0.1f

// ---------------- bf16 helpers (manual RNE) ----------------

__device__ inline unsigned int f2bf1(float x) {
    union { float f; unsigned u; } v; v.f = x;
    unsigned r = v.u + 0x7fffu + ((v.u >> 16) & 1u);
    return r >> 16;
}
__device__ inline unsigned int f2bf2(float lo, float hi) {
    return f2bf1(lo) | (f2bf1(hi) << 16);
}
__device__ inline float bf2f_lo(unsigned u) {
    union { unsigned u; float f; } v; v.u = u << 16; return v.f;
}
__device__ inline float bf2f_hi(unsigned u) {
    union { unsigned u; float f; } v; v.u = u & 0xffff0000u; return v.f;
}

// unaligned-friendly int4 (CSR rows start at arbitrary dword offsets)
struct __attribute__((aligned(4))) i4 { int x, y, z, w; };

// ---------------- CSR build ----------------

__global__ void k_zero(int* __restrict__ cnt) {
    int i = blockIdx.x * blockDim.x + threadIdx.x;
    if (i < N_NODES) cnt[i] = 0;
}

// count + capture per-edge slot order (ord) in one atomic pass
__global__ void k_count(const int* __restrict__ dst, int* __restrict__ cnt,
                        int* __restrict__ ord) {
    int e = blockIdx.x * blockDim.x + threadIdx.x;
    if (e < N_EDGES) ord[e] = atomicAdd(&cnt[dst[e]], 1);
}

// scan1 also produces dinv (fused former k_dinv)
__global__ void k_scan1(const int* __restrict__ cnt, int* __restrict__ rowptr,
                        int* __restrict__ bsum, float* __restrict__ dinv) {
    __shared__ int s[256];
    int t = threadIdx.x;
    int idx = blockIdx.x * 256 + t;
    int v = (idx < N_NODES) ? cnt[idx] : 0;
    if (idx < N_NODES) dinv[idx] = rsqrtf((float)(v + 1));  // +1 self loop
    s[t] = v; __syncthreads();
    for (int off = 1; off < 256; off <<= 1) {
        int add = (t >= off) ? s[t - off] : 0;
        __syncthreads();
        s[t] += add;
        __syncthreads();
    }
    if (idx < N_NODES) rowptr[idx] = s[t] - v;   // exclusive
    if (t == 255) bsum[blockIdx.x] = s[255];     // block total
}

__global__ void k_scan2(int* __restrict__ bsum, int nb) {
    __shared__ int s[256];
    int t = threadIdx.x;
    int v = (t < nb) ? bsum[t] : 0;
    s[t] = v; __syncthreads();
    for (int off = 1; off < 256; off <<= 1) {
        int add = (t >= off) ? s[t - off] : 0;
        __syncthreads();
        s[t] += add;
        __syncthreads();
    }
    if (t < nb) bsum[t] = s[t] - v;              // exclusive block offsets
}

__global__ void k_scan3(int* __restrict__ rowptr, const int* __restrict__ bsum) {
    int idx = blockIdx.x * 256 + threadIdx.x;
    if (idx < N_NODES) rowptr[idx] += bsum[blockIdx.x];
}

// atomic-free fill: pos = rowptr[dst] + ord
__global__ void k_fill(const int* __restrict__ src, const int* __restrict__ dst,
                       const int* __restrict__ ord, const int* __restrict__ rowptr,
                       int* __restrict__ csr_src) {
    int e = blockIdx.x * blockDim.x + threadIdx.x;
    if (e < N_EDGES) {
        csr_src[rowptr[dst[e]] + ord[e]] = src[e];
    }
}

// ---------------- encoder ----------------

__global__ void k_encode(const int* __restrict__ x, const float* __restrict__ emb,
                         float* __restrict__ out) {
    int t = threadIdx.x;
    int d = t & 127, sub = t >> 7;
    int n = blockIdx.x * 2 + sub;
    if (n >= N_NODES) return;
    const int* xr = x + n * NFEAT;
    float s = 0.f;
#pragma unroll
    for (int f = 0; f < NFEAT; ++f) {
        int id = xr[f];
        s += emb[(f * VOCAB + id) * EMB + d];
    }
    out[n * EMB + d] = s;
}

// ---------------- MLP: register-tiled, 32 nodes/block (in-place safe) ----------------

__device__ inline void fma4(float4& acc, float4 a, float4 w0, float4 w1,
                            float4 w2, float4 w3) {
    acc.x = fmaf(a.x, w0.x, fmaf(a.y, w1.x, fmaf(a.z, w2.x, fmaf(a.w, w3.x, acc.x))));
    acc.y = fmaf(a.x, w0.y, fmaf(a.y, w1.y, fmaf(a.z, w2.y, fmaf(a.w, w3.y, acc.y))));
    acc.z = fmaf(a.x, w0.z, fmaf(a.y, w1.z, fmaf(a.z, w2.z, fmaf(a.w, w3.z, acc.z))));
    acc.w = fmaf(a.x, w0.w, fmaf(a.y, w1.w, fmaf(a.z, w2.w, fmaf(a.w, w3.w, acc.w))));
}

__device__ inline float4 relu4(float4 a) {
    return make_float4(fmaxf(a.x, 0.f), fmaxf(a.y, 0.f), fmaxf(a.z, 0.f), fmaxf(a.w, 0.f));
}

// WQ: also write q0 = bf16(dinv*h) and h0b = bf16(h)
template <int RELU, int WQ>
__global__ __launch_bounds__(256) void k_mlp(const float* __restrict__ in,
                                             float* __restrict__ out,
                                             const float* __restrict__ W,
                                             const float* __restrict__ b,
                                             const float* __restrict__ dinv,
                                             uint2* __restrict__ q0out,
                                             uint2* __restrict__ h0bout) {
    __shared__ float4 Wl[EMB * 32];   // 64 KB: Wl[k*32+q] = W[k][4q..4q+3]
    __shared__ float4 hs[32 * 32];    // 16 KB
    int t = threadIdx.x;
    const float4* W4 = (const float4*)W;
    for (int i = t; i < EMB * 32; i += 256) Wl[i] = W4[i];
    int base = blockIdx.x * 32;
    const float4* in4 = (const float4*)in;
    for (int i = t; i < 32 * 32; i += 256) {
        int n = base + (i >> 5);
        hs[i] = (n < N_NODES) ? in4[n * 32 + (i & 31)] : make_float4(0.f, 0.f, 0.f, 0.f);
    }
    __syncthreads();
    int q = t & 31;       // output quad: dims 4q..4q+3
    int g = t >> 5;       // group 0..7: nodes base + 4g .. base + 4g+3
    float4 bias = ((const float4*)b)[q];
    float4 acc0 = bias, acc1 = bias, acc2 = bias, acc3 = bias;
    const float4* h0r = &hs[(g * 4 + 0) * 32];
    const float4* h1r = &hs[(g * 4 + 1) * 32];
    const float4* h2r = &hs[(g * 4 + 2) * 32];
    const float4* h3r = &hs[(g * 4 + 3) * 32];
#pragma unroll 2
    for (int k0 = 0; k0 < EMB; k0 += 4) {
        float4 w0 = Wl[(k0 + 0) * 32 + q];
        float4 w1 = Wl[(k0 + 1) * 32 + q];
        float4 w2 = Wl[(k0 + 2) * 32 + q];
        float4 w3 = Wl[(k0 + 3) * 32 + q];
        int kq = k0 >> 2;
        fma4(acc0, h0r[kq], w0, w1, w2, w3);
        fma4(acc1, h1r[kq], w0, w1, w2, w3);
        fma4(acc2, h2r[kq], w0, w1, w2, w3);
        fma4(acc3, h3r[kq], w0, w1, w2, w3);
    }
    if (RELU) {
        acc0 = relu4(acc0); acc1 = relu4(acc1);
        acc2 = relu4(acc2); acc3 = relu4(acc3);
    }
    float4* out4 = (float4*)out;
    int n0 = base + g * 4;
    if (n0 + 0 < N_NODES) out4[(n0 + 0) * 32 + q] = acc0;
    if (n0 + 1 < N_NODES) out4[(n0 + 1) * 32 + q] = acc1;
    if (n0 + 2 < N_NODES) out4[(n0 + 2) * 32 + q] = acc2;
    if (n0 + 3 < N_NODES) out4[(n0 + 3) * 32 + q] = acc3;
    if (WQ) {
#pragma unroll
        for (int j = 0; j < 4; ++j) {
            int n = n0 + j;
            if (n < N_NODES) {
                float4 a = (j == 0) ? acc0 : (j == 1) ? acc1 : (j == 2) ? acc2 : acc3;
                float s = dinv[n];
                q0out[n * 32 + q] =
                    make_uint2(f2bf2(a.x * s, a.y * s), f2bf2(a.z * s, a.w * s));
                h0bout[n * 32 + q] =
                    make_uint2(f2bf2(a.x, a.y), f2bf2(a.z, a.w));
            }
        }
    }
}

// ---------------- propagation on bf16 q = dinv*h ----------------
// Row = 128 bf16 = 256 B = 16 uint4. Wave per node; lane = (pair 0..3, dq 0..15).
// Indices are wave-uniform: broadcast int4 loads + per-pair cndmask select.
// 16 edges per main trip -> 4 independent row gathers in flight.

#define ACC8(g) \
    a0 += bf2f_lo((g).x); a1 += bf2f_hi((g).x); \
    a2 += bf2f_lo((g).y); a3 += bf2f_hi((g).y); \
    a4 += bf2f_lo((g).z); a5 += bf2f_hi((g).z); \
    a6 += bf2f_lo((g).w); a7 += bf2f_hi((g).w);

#define SEL(iv) (pair == 0 ? (iv).x : pair == 1 ? (iv).y : pair == 2 ? (iv).z : (iv).w)

template <int LAST>
__global__ __launch_bounds__(256) void k_prop(const uint4* __restrict__ qin,
                                              const float4* __restrict__ h0,   // f32 (LAST)
                                              const uint4* __restrict__ h0b,   // bf16
                                              void* __restrict__ outb,
                                              const int* __restrict__ rowptr,
                                              const int* __restrict__ cnt,
                                              const int* __restrict__ csr_src,
                                              const float* __restrict__ dinv) {
    int t = threadIdx.x;
    int lane = t & 63;
    int pair = lane >> 4;              // 0..3: edge sub-slot
    int dq = lane & 15;                // dims 8dq..8dq+7
    int v = blockIdx.x * 4 + (t >> 6); // 12500 * 4 == 50000 exactly
    int start = __builtin_amdgcn_readfirstlane(rowptr[v]);
    int c = __builtin_amdgcn_readfirstlane(cnt[v]);
    const int* cs = csr_src + start;
    float a0 = 0.f, a1 = 0.f, a2 = 0.f, a3 = 0.f;
    float a4 = 0.f, a5 = 0.f, a6 = 0.f, a7 = 0.f;
    int i = 0;
    for (; i + 16 <= c; i += 16) {
        i4 ia = *(const i4*)(cs + i);
        i4 ib = *(const i4*)(cs + i + 4);
        i4 ic = *(const i4*)(cs + i + 8);
        i4 id = *(const i4*)(cs + i + 12);
        int s0 = SEL(ia), s1 = SEL(ib), s2 = SEL(ic), s3 = SEL(id);
        uint4 g0 = qin[s0 * 16 + dq];
        uint4 g1 = qin[s1 * 16 + dq];
        uint4 g2 = qin[s2 * 16 + dq];
        uint4 g3 = qin[s3 * 16 + dq];
        ACC8(g0); ACC8(g1); ACC8(g2); ACC8(g3);
    }
    for (; i + 8 <= c; i += 8) {
        i4 ia = *(const i4*)(cs + i);
        i4 ib = *(const i4*)(cs + i + 4);
        int s0 = SEL(ia), s1 = SEL(ib);
        uint4 g0 = qin[s0 * 16 + dq];
        uint4 g1 = qin[s1 * 16 + dq];
        ACC8(g0); ACC8(g1);
    }
    for (; i < c; i += 4) {
        int e = i + pair;
        if (e < c) {
            uint4 g = qin[cs[e] * 16 + dq];
            ACC8(g);
        }
    }
    // combine the 4 pair-slots
    a0 += __shfl_xor(a0, 16); a0 += __shfl_xor(a0, 32);
    a1 += __shfl_xor(a1, 16); a1 += __shfl_xor(a1, 32);
    a2 += __shfl_xor(a2, 16); a2 += __shfl_xor(a2, 32);
    a3 += __shfl_xor(a3, 16); a3 += __shfl_xor(a3, 32);
    a4 += __shfl_xor(a4, 16); a4 += __shfl_xor(a4, 32);
    a5 += __shfl_xor(a5, 16); a5 += __shfl_xor(a5, 32);
    a6 += __shfl_xor(a6, 16); a6 += __shfl_xor(a6, 32);
    a7 += __shfl_xor(a7, 16); a7 += __shfl_xor(a7, 32);

    float dv = dinv[v];
    uint4 qv = qin[v * 16 + dq];  // self term
    float s0 = a0 + bf2f_lo(qv.x), s1 = a1 + bf2f_hi(qv.x);
    float s2 = a2 + bf2f_lo(qv.y), s3 = a3 + bf2f_hi(qv.y);
    float s4 = a4 + bf2f_lo(qv.z), s5 = a5 + bf2f_hi(qv.z);
    float s6 = a6 + bf2f_lo(qv.w), s7 = a7 + bf2f_hi(qv.w);
    const float K = 1.f - ALPHA;

    if (LAST) {
        float4 hlo = h0[v * 32 + 2 * dq];
        float4 hhi = h0[v * 32 + 2 * dq + 1];
        float h_0 = K * dv * s0 + ALPHA * hlo.x;
        float h_1 = K * dv * s1 + ALPHA * hlo.y;
        float h_2 = K * dv * s2 + ALPHA * hlo.z;
        float h_3 = K * dv * s3 + ALPHA * hlo.w;
        float h_4 = K * dv * s4 + ALPHA * hhi.x;
        float h_5 = K * dv * s5 + ALPHA * hhi.y;
        float h_6 = K * dv * s6 + ALPHA * hhi.z;
        float h_7 = K * dv * s7 + ALPHA * hhi.w;
        if (pair < 2) {
            float4 wv = (pair == 0) ? make_float4(h_0, h_1, h_2, h_3)
                                    : make_float4(h_4, h_5, h_6, h_7);
            ((float4*)outb)[v * 32 + 2 * dq + pair] = wv;
        }
    } else {
        uint4 hv = h0b[v * 16 + dq];
        float h_0 = K * dv * s0 + ALPHA * bf2f_lo(hv.x);
        float h_1 = K * dv * s1 + ALPHA * bf2f_hi(hv.x);
        float h_2 = K * dv * s2 + ALPHA * bf2f_lo(hv.y);
        float h_3 = K * dv * s3 + ALPHA * bf2f_hi(hv.y);
        float h_4 = K * dv * s4 + ALPHA * bf2f_lo(hv.z);
        float h_5 = K * dv * s5 + ALPHA * bf2f_hi(hv.z);
        float h_6 = K * dv * s6 + ALPHA * bf2f_lo(hv.w);
        float h_7 = K * dv * s7 + ALPHA * bf2f_hi(hv.w);
        if (pair == 0) {
            uint4 wv;
            wv.x = f2bf2(h_0 * dv, h_1 * dv);
            wv.y = f2bf2(h_2 * dv, h_3 * dv);
            wv.z = f2bf2(h_4 * dv, h_5 * dv);
            wv.w = f2bf2(h_6 * dv, h_7 * dv);
            ((uint4*)outb)[v * 16 + dq] = wv;
        }
    }
}

// ---------------- host ----------------

extern "C" void kernel_launch(void* const* d_in, const int* in_sizes, int n_in,
                              void* d_out, int out_size, void* d_ws, size_t ws_size,
                              hipStream_t stream) {
    const int*   x    = (const int*)d_in[0];             // [N, 9]
    const int*   ei   = (const int*)d_in[1];             // [2, E]
    const float* emb  = (const float*)d_in[2];           // [9, 119, 128]
    const float* Ws   = (const float*)d_in[3];           // [3, 128, 128]
    const float* bs   = (const float*)d_in[4];           // [3, 128]
    float* out = (float*)d_out;                          // [N, 128] f32

    const int* src = ei;
    const int* dst = ei + N_EDGES;

    // workspace carve-up (byte-based, 256B-aligned chunks)
    char* w = (char*)d_ws;
    size_t off = 0;
    auto alloc = [&](size_t bytes) {
        void* p = w + off;
        off += (bytes + 255) & ~(size_t)255;
        return p;
    };
    float* h0      = (float*)alloc((size_t)N_NODES * EMB * 4);
    float* hT      = (float*)alloc((size_t)N_NODES * EMB * 4);  // MLP in-place chain
    void*  qA      = alloc((size_t)N_NODES * EMB * 2);   // bf16
    void*  qB      = alloc((size_t)N_NODES * EMB * 2);   // bf16
    void*  h0b     = alloc((size_t)N_NODES * EMB * 2);   // bf16 copy of h0
    float* dinv    = (float*)alloc(N_NODES * 4);
    int*   cnt     = (int*)alloc(N_NODES * 4);
    int*   rowptr  = (int*)alloc(N_NODES * 4);
    int*   bsum    = (int*)alloc(256 * 4);
    int*   csr_src = (int*)alloc(N_EDGES * 4);
    int*   ord     = (int*)alloc(N_EDGES * 4);
    (void)ws_size; (void)n_in; (void)in_sizes; (void)out_size;

    const int NB_N  = (N_NODES + 255) / 256;   // 196
    const int NB_E  = (N_EDGES + 255) / 256;   // 3125
    const int NB_2N = (N_NODES + 1) / 2;       // 25000 (encode)
    const int NB_M  = (N_NODES + 31) / 32;     // 1563 (mlp)
    const int NB_P  = N_NODES / 4;             // 12500 (prop, exact)

    // CSR build
    k_zero<<<NB_N, 256, 0, stream>>>(cnt);
    k_count<<<NB_E, 256, 0, stream>>>(dst, cnt, ord);
    k_scan1<<<NB_N, 256, 0, stream>>>(cnt, rowptr, bsum, dinv);
    k_scan2<<<1, 256, 0, stream>>>(bsum, NB_N);
    k_scan3<<<NB_N, 256, 0, stream>>>(rowptr, bsum);
    k_fill<<<NB_E, 256, 0, stream>>>(src, dst, ord, rowptr, csr_src);

    // encoder + 3-layer MLP (in-place on hT; last layer writes h0 + bf16 q0/h0b)
    k_encode<<<NB_2N, 256, 0, stream>>>(x, emb, hT);
    k_mlp<1, 0><<<NB_M, 256, 0, stream>>>(hT, hT, Ws + 0 * EMB * EMB, bs + 0 * EMB,
                                          nullptr, nullptr, nullptr);
    k_mlp<1, 0><<<NB_M, 256, 0, stream>>>(hT, hT, Ws + 1 * EMB * EMB, bs + 1 * EMB,
                                          nullptr, nullptr, nullptr);
    k_mlp<0, 1><<<NB_M, 256, 0, stream>>>(hT, h0, Ws + 2 * EMB * EMB, bs + 2 * EMB,
                                          dinv, (uint2*)qA, (uint2*)h0b);

    // 10 propagation iterations on bf16 q; last writes f32 h to d_out
    const uint4* qin = (const uint4*)qA;
    for (int i = 0; i < NITER; ++i) {
        if (i == NITER - 1) {
            k_prop<1><<<NB_P, 256, 0, stream>>>(qin, (const float4*)h0,
                                                (const uint4*)h0b, out,
                                                rowptr, cnt, csr_src, dinv);
        } else {
            void* qo = (i & 1) ? qA : qB;
            k_prop<0><<<NB_P, 256, 0, stream>>>(qin, (const float4*)h0,
                                                (const uint4*)h0b, qo,
                                                rowptr, cnt, csr_src, dinv);
            qin = (const uint4*)qo;
        }
    }
}

// Round 7
// 584.494 us; speedup vs baseline: 3.3115x; 1.0089x over previous
//
#include <hip/hip_runtime.h>

#define N_NODES 50000
#define N_EDGES 800000
#define EMB 128
#define NFEAT 9
#define VOCAB 119
#define NITER 10
#define ALPHA 0.1f

// ---------------- bf16 helpers (manual RNE) ----------------

__device__ inline unsigned int f2bf1(float x) {
    union { float f; unsigned u; } v; v.f = x;
    unsigned r = v.u + 0x7fffu + ((v.u >> 16) & 1u);
    return r >> 16;
}
__device__ inline unsigned int f2bf2(float lo, float hi) {
    return f2bf1(lo) | (f2bf1(hi) << 16);
}
__device__ inline float bf2f_lo(unsigned u) {
    union { unsigned u; float f; } v; v.u = u << 16; return v.f;
}
__device__ inline float bf2f_hi(unsigned u) {
    union { unsigned u; float f; } v; v.u = u & 0xffff0000u; return v.f;
}

// unaligned-friendly int4 (CSR rows start at arbitrary dword offsets)
struct __attribute__((aligned(4))) i4 { int x, y, z, w; };

// ---------------- CSR build ----------------

__global__ void k_zero(int* __restrict__ cnt) {
    int i = blockIdx.x * blockDim.x + threadIdx.x;
    if (i < N_NODES) cnt[i] = 0;
}

// count + capture per-edge slot order (ord) in one atomic pass
__global__ void k_count(const int* __restrict__ dst, int* __restrict__ cnt,
                        int* __restrict__ ord) {
    int e = blockIdx.x * blockDim.x + threadIdx.x;
    if (e < N_EDGES) ord[e] = atomicAdd(&cnt[dst[e]], 1);
}

// scan1 also produces dinv (fused former k_dinv)
__global__ void k_scan1(const int* __restrict__ cnt, int* __restrict__ rowptr,
                        int* __restrict__ bsum, float* __restrict__ dinv) {
    __shared__ int s[256];
    int t = threadIdx.x;
    int idx = blockIdx.x * 256 + t;
    int v = (idx < N_NODES) ? cnt[idx] : 0;
    if (idx < N_NODES) dinv[idx] = rsqrtf((float)(v + 1));  // +1 self loop
    s[t] = v; __syncthreads();
    for (int off = 1; off < 256; off <<= 1) {
        int add = (t >= off) ? s[t - off] : 0;
        __syncthreads();
        s[t] += add;
        __syncthreads();
    }
    if (idx < N_NODES) rowptr[idx] = s[t] - v;   // exclusive
    if (t == 255) bsum[blockIdx.x] = s[255];     // block total
}

__global__ void k_scan2(int* __restrict__ bsum, int nb) {
    __shared__ int s[256];
    int t = threadIdx.x;
    int v = (t < nb) ? bsum[t] : 0;
    s[t] = v; __syncthreads();
    for (int off = 1; off < 256; off <<= 1) {
        int add = (t >= off) ? s[t - off] : 0;
        __syncthreads();
        s[t] += add;
        __syncthreads();
    }
    if (t < nb) bsum[t] = s[t] - v;              // exclusive block offsets
}

__global__ void k_scan3(int* __restrict__ rowptr, const int* __restrict__ bsum) {
    int idx = blockIdx.x * 256 + threadIdx.x;
    if (idx < N_NODES) rowptr[idx] += bsum[blockIdx.x];
}

// atomic-free fill: pos = rowptr[dst] + ord
__global__ void k_fill(const int* __restrict__ src, const int* __restrict__ dst,
                       const int* __restrict__ ord, const int* __restrict__ rowptr,
                       int* __restrict__ csr_src) {
    int e = blockIdx.x * blockDim.x + threadIdx.x;
    if (e < N_EDGES) {
        csr_src[rowptr[dst[e]] + ord[e]] = src[e];
    }
}

// ---------------- encoder ----------------

__global__ void k_encode(const int* __restrict__ x, const float* __restrict__ emb,
                         float* __restrict__ out) {
    int t = threadIdx.x;
    int d = t & 127, sub = t >> 7;
    int n = blockIdx.x * 2 + sub;
    if (n >= N_NODES) return;
    const int* xr = x + n * NFEAT;
    float s = 0.f;
#pragma unroll
    for (int f = 0; f < NFEAT; ++f) {
        int id = xr[f];
        s += emb[(f * VOCAB + id) * EMB + d];
    }
    out[n * EMB + d] = s;
}

// ---------------- MLP: register-tiled, 32 nodes/block ----------------
// W read from GLOBAL (wave-uniform addresses -> L1 broadcast; only 64 KB shared
// by all blocks). Only the 16 KB h-tile lives in LDS -> occupancy is VGPR-bound
// instead of 2-blocks/CU LDS-bound.

__device__ inline void fma4(float4& acc, float4 a, float4 w0, float4 w1,
                            float4 w2, float4 w3) {
    acc.x = fmaf(a.x, w0.x, fmaf(a.y, w1.x, fmaf(a.z, w2.x, fmaf(a.w, w3.x, acc.x))));
    acc.y = fmaf(a.x, w0.y, fmaf(a.y, w1.y, fmaf(a.z, w2.y, fmaf(a.w, w3.y, acc.y))));
    acc.z = fmaf(a.x, w0.z, fmaf(a.y, w1.z, fmaf(a.z, w2.z, fmaf(a.w, w3.z, acc.z))));
    acc.w = fmaf(a.x, w0.w, fmaf(a.y, w1.w, fmaf(a.z, w2.w, fmaf(a.w, w3.w, acc.w))));
}

__device__ inline float4 relu4(float4 a) {
    return make_float4(fmaxf(a.x, 0.f), fmaxf(a.y, 0.f), fmaxf(a.z, 0.f), fmaxf(a.w, 0.f));
}

// WQ: also write q0 = bf16(dinv*h) and h0b = bf16(h)
template <int RELU, int WQ>
__global__ __launch_bounds__(256) void k_mlp(const float* __restrict__ in,
                                             float* __restrict__ out,
                                             const float* __restrict__ W,
                                             const float* __restrict__ b,
                                             const float* __restrict__ dinv,
                                             uint2* __restrict__ q0out,
                                             uint2* __restrict__ h0bout) {
    __shared__ float4 hs[32 * 32];    // 16 KB
    int t = threadIdx.x;
    int base = blockIdx.x * 32;
    const float4* in4 = (const float4*)in;
    for (int i = t; i < 32 * 32; i += 256) {
        int n = base + (i >> 5);
        hs[i] = (n < N_NODES) ? in4[n * 32 + (i & 31)] : make_float4(0.f, 0.f, 0.f, 0.f);
    }
    __syncthreads();
    int q = t & 31;       // output quad: dims 4q..4q+3
    int g = t >> 5;       // group 0..7: nodes base + 4g .. base + 4g+3
    const float4* Wq = (const float4*)W + q;   // column quad, stride 32 float4 per k
    float4 bias = ((const float4*)b)[q];
    float4 acc0 = bias, acc1 = bias, acc2 = bias, acc3 = bias;
    const float4* h0r = &hs[(g * 4 + 0) * 32];
    const float4* h1r = &hs[(g * 4 + 1) * 32];
    const float4* h2r = &hs[(g * 4 + 2) * 32];
    const float4* h3r = &hs[(g * 4 + 3) * 32];
#pragma unroll 2
    for (int k0 = 0; k0 < EMB; k0 += 4) {
        float4 w0 = Wq[(k0 + 0) * 32];
        float4 w1 = Wq[(k0 + 1) * 32];
        float4 w2 = Wq[(k0 + 2) * 32];
        float4 w3 = Wq[(k0 + 3) * 32];
        int kq = k0 >> 2;
        fma4(acc0, h0r[kq], w0, w1, w2, w3);
        fma4(acc1, h1r[kq], w0, w1, w2, w3);
        fma4(acc2, h2r[kq], w0, w1, w2, w3);
        fma4(acc3, h3r[kq], w0, w1, w2, w3);
    }
    if (RELU) {
        acc0 = relu4(acc0); acc1 = relu4(acc1);
        acc2 = relu4(acc2); acc3 = relu4(acc3);
    }
    float4* out4 = (float4*)out;
    int n0 = base + g * 4;
    if (n0 + 0 < N_NODES) out4[(n0 + 0) * 32 + q] = acc0;
    if (n0 + 1 < N_NODES) out4[(n0 + 1) * 32 + q] = acc1;
    if (n0 + 2 < N_NODES) out4[(n0 + 2) * 32 + q] = acc2;
    if (n0 + 3 < N_NODES) out4[(n0 + 3) * 32 + q] = acc3;
    if (WQ) {
#pragma unroll
        for (int j = 0; j < 4; ++j) {
            int n = n0 + j;
            if (n < N_NODES) {
                float4 a = (j == 0) ? acc0 : (j == 1) ? acc1 : (j == 2) ? acc2 : acc3;
                float s = dinv[n];
                q0out[n * 32 + q] =
                    make_uint2(f2bf2(a.x * s, a.y * s), f2bf2(a.z * s, a.w * s));
                h0bout[n * 32 + q] =
                    make_uint2(f2bf2(a.x, a.y), f2bf2(a.z, a.w));
            }
        }
    }
}

// ---------------- propagation on bf16 q = dinv*h ----------------
// Row = 128 bf16 = 256 B = 16 uint4. Wave per node; lane = (pair 0..3, dq 0..15).
// Indices wave-uniform (readfirstlane base + i4 loads); main loop 32 edges/trip
// -> 8 independent 1024B row-gathers in flight per wave.

#define ACC8(g) \
    a0 += bf2f_lo((g).x); a1 += bf2f_hi((g).x); \
    a2 += bf2f_lo((g).y); a3 += bf2f_hi((g).y); \
    a4 += bf2f_lo((g).z); a5 += bf2f_hi((g).z); \
    a6 += bf2f_lo((g).w); a7 += bf2f_hi((g).w);

#define SEL(iv) (pair == 0 ? (iv).x : pair == 1 ? (iv).y : pair == 2 ? (iv).z : (iv).w)

template <int LAST>
__global__ __launch_bounds__(256) void k_prop(const uint4* __restrict__ qin,
                                              const float4* __restrict__ h0,   // f32 (LAST)
                                              const uint4* __restrict__ h0b,   // bf16
                                              void* __restrict__ outb,
                                              const int* __restrict__ rowptr,
                                              const int* __restrict__ cnt,
                                              const int* __restrict__ csr_src,
                                              const float* __restrict__ dinv) {
    int t = threadIdx.x;
    int lane = t & 63;
    int pair = lane >> 4;              // 0..3: edge sub-slot
    int dq = lane & 15;                // dims 8dq..8dq+7
    int v = blockIdx.x * 4 + (t >> 6); // 12500 * 4 == 50000 exactly
    int start = __builtin_amdgcn_readfirstlane(rowptr[v]);
    int c = __builtin_amdgcn_readfirstlane(cnt[v]);
    const int* cs = csr_src + start;

    // hoist self/anchor loads: latency overlaps the edge loop
    float dv = dinv[v];
    uint4 qv = qin[v * 16 + dq];
    float4 hlo, hhi; uint4 hvb;
    if (LAST) {
        hlo = h0[v * 32 + 2 * dq];
        hhi = h0[v * 32 + 2 * dq + 1];
    } else {
        hvb = h0b[v * 16 + dq];
    }

    float a0 = 0.f, a1 = 0.f, a2 = 0.f, a3 = 0.f;
    float a4 = 0.f, a5 = 0.f, a6 = 0.f, a7 = 0.f;
    int i = 0;
    for (; i + 32 <= c; i += 32) {
        i4 ia = *(const i4*)(cs + i);
        i4 ib = *(const i4*)(cs + i + 4);
        i4 ic = *(const i4*)(cs + i + 8);
        i4 id = *(const i4*)(cs + i + 12);
        i4 ie = *(const i4*)(cs + i + 16);
        i4 ifq = *(const i4*)(cs + i + 20);
        i4 ig = *(const i4*)(cs + i + 24);
        i4 ih = *(const i4*)(cs + i + 28);
        int s0 = SEL(ia), s1 = SEL(ib), s2 = SEL(ic), s3 = SEL(id);
        int s4 = SEL(ie), s5 = SEL(ifq), s6 = SEL(ig), s7 = SEL(ih);
        uint4 g0 = qin[s0 * 16 + dq];
        uint4 g1 = qin[s1 * 16 + dq];
        uint4 g2 = qin[s2 * 16 + dq];
        uint4 g3 = qin[s3 * 16 + dq];
        uint4 g4 = qin[s4 * 16 + dq];
        uint4 g5 = qin[s5 * 16 + dq];
        uint4 g6 = qin[s6 * 16 + dq];
        uint4 g7 = qin[s7 * 16 + dq];
        ACC8(g0); ACC8(g1); ACC8(g2); ACC8(g3);
        ACC8(g4); ACC8(g5); ACC8(g6); ACC8(g7);
    }
    for (; i + 8 <= c; i += 8) {
        i4 ia = *(const i4*)(cs + i);
        i4 ib = *(const i4*)(cs + i + 4);
        int s0 = SEL(ia), s1 = SEL(ib);
        uint4 g0 = qin[s0 * 16 + dq];
        uint4 g1 = qin[s1 * 16 + dq];
        ACC8(g0); ACC8(g1);
    }
    for (; i < c; i += 4) {
        int e = i + pair;
        if (e < c) {
            uint4 g = qin[cs[e] * 16 + dq];
            ACC8(g);
        }
    }
    // combine the 4 pair-slots
    a0 += __shfl_xor(a0, 16); a0 += __shfl_xor(a0, 32);
    a1 += __shfl_xor(a1, 16); a1 += __shfl_xor(a1, 32);
    a2 += __shfl_xor(a2, 16); a2 += __shfl_xor(a2, 32);
    a3 += __shfl_xor(a3, 16); a3 += __shfl_xor(a3, 32);
    a4 += __shfl_xor(a4, 16); a4 += __shfl_xor(a4, 32);
    a5 += __shfl_xor(a5, 16); a5 += __shfl_xor(a5, 32);
    a6 += __shfl_xor(a6, 16); a6 += __shfl_xor(a6, 32);
    a7 += __shfl_xor(a7, 16); a7 += __shfl_xor(a7, 32);

    float s0 = a0 + bf2f_lo(qv.x), s1 = a1 + bf2f_hi(qv.x);
    float s2 = a2 + bf2f_lo(qv.y), s3 = a3 + bf2f_hi(qv.y);
    float s4 = a4 + bf2f_lo(qv.z), s5 = a5 + bf2f_hi(qv.z);
    float s6 = a6 + bf2f_lo(qv.w), s7 = a7 + bf2f_hi(qv.w);
    const float K = 1.f - ALPHA;

    if (LAST) {
        float h_0 = K * dv * s0 + ALPHA * hlo.x;
        float h_1 = K * dv * s1 + ALPHA * hlo.y;
        float h_2 = K * dv * s2 + ALPHA * hlo.z;
        float h_3 = K * dv * s3 + ALPHA * hlo.w;
        float h_4 = K * dv * s4 + ALPHA * hhi.x;
        float h_5 = K * dv * s5 + ALPHA * hhi.y;
        float h_6 = K * dv * s6 + ALPHA * hhi.z;
        float h_7 = K * dv * s7 + ALPHA * hhi.w;
        if (pair < 2) {
            float4 wv = (pair == 0) ? make_float4(h_0, h_1, h_2, h_3)
                                    : make_float4(h_4, h_5, h_6, h_7);
            ((float4*)outb)[v * 32 + 2 * dq + pair] = wv;
        }
    } else {
        float h_0 = K * dv * s0 + ALPHA * bf2f_lo(hvb.x);
        float h_1 = K * dv * s1 + ALPHA * bf2f_hi(hvb.x);
        float h_2 = K * dv * s2 + ALPHA * bf2f_lo(hvb.y);
        float h_3 = K * dv * s3 + ALPHA * bf2f_hi(hvb.y);
        float h_4 = K * dv * s4 + ALPHA * bf2f_lo(hvb.z);
        float h_5 = K * dv * s5 + ALPHA * bf2f_hi(hvb.z);
        float h_6 = K * dv * s6 + ALPHA * bf2f_lo(hvb.w);
        float h_7 = K * dv * s7 + ALPHA * bf2f_hi(hvb.w);
        if (pair == 0) {
            uint4 wv;
            wv.x = f2bf2(h_0 * dv, h_1 * dv);
            wv.y = f2bf2(h_2 * dv, h_3 * dv);
            wv.z = f2bf2(h_4 * dv, h_5 * dv);
            wv.w = f2bf2(h_6 * dv, h_7 * dv);
            ((uint4*)outb)[v * 16 + dq] = wv;
        }
    }
}

// ---------------- host ----------------

extern "C" void kernel_launch(void* const* d_in, const int* in_sizes, int n_in,
                              void* d_out, int out_size, void* d_ws, size_t ws_size,
                              hipStream_t stream) {
    const int*   x    = (const int*)d_in[0];             // [N, 9]
    const int*   ei   = (const int*)d_in[1];             // [2, E]
    const float* emb  = (const float*)d_in[2];           // [9, 119, 128]
    const float* Ws   = (const float*)d_in[3];           // [3, 128, 128]
    const float* bs   = (const float*)d_in[4];           // [3, 128]
    float* out = (float*)d_out;                          // [N, 128] f32

    const int* src = ei;
    const int* dst = ei + N_EDGES;

    // workspace carve-up (byte-based, 256B-aligned chunks)
    char* w = (char*)d_ws;
    size_t off = 0;
    auto alloc = [&](size_t bytes) {
        void* p = w + off;
        off += (bytes + 255) & ~(size_t)255;
        return p;
    };
    float* h0      = (float*)alloc((size_t)N_NODES * EMB * 4);
    float* hT      = (float*)alloc((size_t)N_NODES * EMB * 4);  // MLP in-place chain
    void*  qA      = alloc((size_t)N_NODES * EMB * 2);   // bf16
    void*  qB      = alloc((size_t)N_NODES * EMB * 2);   // bf16
    void*  h0b     = alloc((size_t)N_NODES * EMB * 2);   // bf16 copy of h0
    float* dinv    = (float*)alloc(N_NODES * 4);
    int*   cnt     = (int*)alloc(N_NODES * 4);
    int*   rowptr  = (int*)alloc(N_NODES * 4);
    int*   bsum    = (int*)alloc(256 * 4);
    int*   csr_src = (int*)alloc(N_EDGES * 4);
    int*   ord     = (int*)alloc(N_EDGES * 4);
    (void)ws_size; (void)n_in; (void)in_sizes; (void)out_size;

    const int NB_N  = (N_NODES + 255) / 256;   // 196
    const int NB_E  = (N_EDGES + 255) / 256;   // 3125
    const int NB_2N = (N_NODES + 1) / 2;       // 25000 (encode)
    const int NB_M  = (N_NODES + 31) / 32;     // 1563 (mlp)
    const int NB_P  = N_NODES / 4;             // 12500 (prop, exact)

    // CSR build
    k_zero<<<NB_N, 256, 0, stream>>>(cnt);
    k_count<<<NB_E, 256, 0, stream>>>(dst, cnt, ord);
    k_scan1<<<NB_N, 256, 0, stream>>>(cnt, rowptr, bsum, dinv);
    k_scan2<<<1, 256, 0, stream>>>(bsum, NB_N);
    k_scan3<<<NB_N, 256, 0, stream>>>(rowptr, bsum);
    k_fill<<<NB_E, 256, 0, stream>>>(src, dst, ord, rowptr, csr_src);

    // encoder + 3-layer MLP (in-place on hT; last layer writes h0 + bf16 q0/h0b)
    k_encode<<<NB_2N, 256, 0, stream>>>(x, emb, hT);
    k_mlp<1, 0><<<NB_M, 256, 0, stream>>>(hT, hT, Ws + 0 * EMB * EMB, bs + 0 * EMB,
                                          nullptr, nullptr, nullptr);
    k_mlp<1, 0><<<NB_M, 256, 0, stream>>>(hT, hT, Ws + 1 * EMB * EMB, bs + 1 * EMB,
                                          nullptr, nullptr, nullptr);
    k_mlp<0, 1><<<NB_M, 256, 0, stream>>>(hT, h0, Ws + 2 * EMB * EMB, bs + 2 * EMB,
                                          dinv, (uint2*)qA, (uint2*)h0b);

    // 10 propagation iterations on bf16 q; last writes f32 h to d_out
    const uint4* qin = (const uint4*)qA;
    for (int i = 0; i < NITER; ++i) {
        if (i == NITER - 1) {
            k_prop<1><<<NB_P, 256, 0, stream>>>(qin, (const float4*)h0,
                                                (const uint4*)h0b, out,
                                                rowptr, cnt, csr_src, dinv);
        } else {
            void* qo = (i & 1) ? qA : qB;
            k_prop<0><<<NB_P, 256, 0, stream>>>(qin, (const float4*)h0,
                                                (const uint4*)h0b, qo,
                                                rowptr, cnt, csr_src, dinv);
            qin = (const uint4*)qo;
        }
    }
}

// Round 9
// 554.048 us; speedup vs baseline: 3.4935x; 1.0550x over previous
//
#include <hip/hip_runtime.h>

#define N_NODES 50000
#define NPAD    50048   // 782 * 64, MFMA-tile padded
#define N_EDGES 800000
#define EMB 128
#define NFEAT 9
#define VOCAB 119
#define NITER 10
#define ALPHA 0.1f

typedef __attribute__((ext_vector_type(8))) short bf16x8;
typedef __attribute__((ext_vector_type(4))) float f32x4;

// ---------------- bf16 helpers (manual RNE) ----------------

__device__ inline unsigned int f2bf1(float x) {
    union { float f; unsigned u; } v; v.f = x;
    unsigned r = v.u + 0x7fffu + ((v.u >> 16) & 1u);
    return r >> 16;
}
__device__ inline unsigned int f2bf2(float lo, float hi) {
    return f2bf1(lo) | (f2bf1(hi) << 16);
}
__device__ inline float bf2f_lo(unsigned u) {
    union { unsigned u; float f; } v; v.u = u << 16; return v.f;
}
__device__ inline float bf2f_hi(unsigned u) {
    union { unsigned u; float f; } v; v.u = u & 0xffff0000u; return v.f;
}

// unaligned-friendly int4 (CSR rows start at arbitrary dword offsets)
struct __attribute__((aligned(4))) i4 { int x, y, z, w; };

// ---------------- CSR build ----------------

__global__ void k_zero(int* __restrict__ cnt) {
    int i = blockIdx.x * blockDim.x + threadIdx.x;
    if (i < N_NODES) cnt[i] = 0;
}

__global__ void k_count(const int* __restrict__ dst, int* __restrict__ cnt,
                        int* __restrict__ ord) {
    int e = blockIdx.x * blockDim.x + threadIdx.x;
    if (e < N_EDGES) ord[e] = atomicAdd(&cnt[dst[e]], 1);
}

__global__ void k_scan1(const int* __restrict__ cnt, int* __restrict__ rowptr,
                        int* __restrict__ bsum, float* __restrict__ dinv) {
    __shared__ int s[256];
    int t = threadIdx.x;
    int idx = blockIdx.x * 256 + t;
    int v = (idx < N_NODES) ? cnt[idx] : 0;
    if (idx < N_NODES) dinv[idx] = rsqrtf((float)(v + 1));  // +1 self loop
    s[t] = v; __syncthreads();
    for (int off = 1; off < 256; off <<= 1) {
        int add = (t >= off) ? s[t - off] : 0;
        __syncthreads();
        s[t] += add;
        __syncthreads();
    }
    if (idx < N_NODES) rowptr[idx] = s[t] - v;   // exclusive
    if (t == 255) bsum[blockIdx.x] = s[255];     // block total
}

__global__ void k_scan2(int* __restrict__ bsum, int nb) {
    __shared__ int s[256];
    int t = threadIdx.x;
    int v = (t < nb) ? bsum[t] : 0;
    s[t] = v; __syncthreads();
    for (int off = 1; off < 256; off <<= 1) {
        int add = (t >= off) ? s[t - off] : 0;
        __syncthreads();
        s[t] += add;
        __syncthreads();
    }
    if (t < nb) bsum[t] = s[t] - v;              // exclusive block offsets
}

__global__ void k_scan3(int* __restrict__ rowptr, const int* __restrict__ bsum) {
    int idx = blockIdx.x * 256 + threadIdx.x;
    if (idx < N_NODES) rowptr[idx] += bsum[blockIdx.x];
}

__global__ void k_fill(const int* __restrict__ src, const int* __restrict__ dst,
                       const int* __restrict__ ord, const int* __restrict__ rowptr,
                       int* __restrict__ csr_src) {
    int e = blockIdx.x * blockDim.x + threadIdx.x;
    if (e < N_EDGES) {
        csr_src[rowptr[dst[e]] + ord[e]] = src[e];
    }
}

// ---------------- W prep: WT[l][n][k] = bf16(W[l][k][n]) ----------------

__global__ void k_wprep(const float* __restrict__ W, ushort* __restrict__ WT) {
    int l = blockIdx.x >> 7;        // layer 0..2
    int n = blockIdx.x & 127;
    int k = threadIdx.x;            // 128 threads
    WT[(l * 128 + n) * 128 + k] = (ushort)f2bf1(W[(l * 128 + k) * 128 + n]);
}

// ---------------- encoder -> bf16 ----------------

__global__ void k_encode(const int* __restrict__ x, const float* __restrict__ emb,
                         unsigned* __restrict__ hb) {
    int t = threadIdx.x;
    int sub = t >> 6;                   // node 0..3
    int dq = t & 63;                    // dim pair
    int n = blockIdx.x * 4 + sub;       // grid 12500 -> exact 50000
    const int* xr = x + n * NFEAT;
    float s0 = 0.f, s1 = 0.f;
#pragma unroll
    for (int f = 0; f < NFEAT; ++f) {
        const float2 e = *(const float2*)&emb[(f * VOCAB + xr[f]) * EMB + 2 * dq];
        s0 += e.x; s1 += e.y;
    }
    hb[n * 64 + dq] = f2bf2(s0, s1);
}

// ---------------- MLP via MFMA: 64 nodes/block, 4 waves ----------------
// Wave w owns rows base+w*16 .. +16. Per wave: A-frags (4 K-chunks of its own
// 16 rows), 8 output tiles of 16 cols; B from WT (bf16, n-major). C/D layout
// (verified m89): col = lane&15, row = (lane>>4)*4 + reg.

template <int RELU, int WQ>
__global__ __launch_bounds__(256) void k_mlp_mfma(
        const uint4* __restrict__ inb,     // bf16 [NPAD][128], row = 16 uint4
        uint4* __restrict__ outb,          // bf16 out (may == inb; per-wave in-place safe)
        const uint4* __restrict__ WT4,     // bf16 [128][128] n-major
        const float* __restrict__ bias,
        const float* __restrict__ dinv,
        float* __restrict__ h0out,         // WQ: f32
        ushort* __restrict__ q0out,        // WQ: bf16 dinv*h
        ushort* __restrict__ h0bout) {     // WQ: bf16 h
    int t = threadIdx.x;
    int w = t >> 6;
    int l = t & 63;
    int lr = l & 15;       // A-row / B-col / C-col within tile
    int kg = l >> 4;       // k-group 0..3
    int base = blockIdx.x * 64 + w * 16;
    union U { uint4 u; bf16x8 b; };

    int arow = base + lr;
    bf16x8 afrag[4];
#pragma unroll
    for (int kc = 0; kc < 4; ++kc) {
        U cu; cu.u = inb[arow * 16 + kc * 4 + kg];
        afrag[kc] = cu.b;
    }

    f32x4 acc[8];
#pragma unroll
    for (int nt = 0; nt < 8; ++nt) {
        float bv = bias[nt * 16 + lr];
        acc[nt] = (f32x4){bv, bv, bv, bv};
    }

#pragma unroll
    for (int kc = 0; kc < 4; ++kc) {
#pragma unroll
        for (int nt = 0; nt < 8; ++nt) {
            U cu; cu.u = WT4[(nt * 16 + lr) * 16 + kc * 4 + kg];
            acc[nt] = __builtin_amdgcn_mfma_f32_16x16x32_bf16(afrag[kc], cu.b,
                                                              acc[nt], 0, 0, 0);
        }
    }

    int orow = base + kg * 4;   // rows orow..orow+3 (reg index r)
    float dv[4];
    if (WQ) {
#pragma unroll
        for (int r = 0; r < 4; ++r) dv[r] = dinv[orow + r];
    }
#pragma unroll
    for (int nt = 0; nt < 8; ++nt) {
        int n = nt * 16 + lr;
#pragma unroll
        for (int r = 0; r < 4; ++r) {
            float val = acc[nt][r];
            if (RELU) val = fmaxf(val, 0.f);
            if (WQ) {
                h0out[(orow + r) * 128 + n] = val;
                q0out[(orow + r) * 128 + n] = (ushort)f2bf1(val * dv[r]);
                h0bout[(orow + r) * 128 + n] = (ushort)f2bf1(val);
            } else {
                ((ushort*)outb)[(orow + r) * 128 + n] = (ushort)f2bf1(val);
            }
        }
    }
}

// ---------------- propagation on bf16 q = dinv*h ----------------

#define ACC8(g) \
    a0 += bf2f_lo((g).x); a1 += bf2f_hi((g).x); \
    a2 += bf2f_lo((g).y); a3 += bf2f_hi((g).y); \
    a4 += bf2f_lo((g).z); a5 += bf2f_hi((g).z); \
    a6 += bf2f_lo((g).w); a7 += bf2f_hi((g).w);

#define SEL(iv) (pair == 0 ? (iv).x : pair == 1 ? (iv).y : pair == 2 ? (iv).z : (iv).w)

template <int LAST>
__global__ __launch_bounds__(256) void k_prop(const uint4* __restrict__ qin,
                                              const float4* __restrict__ h0,   // f32 (LAST)
                                              const uint4* __restrict__ h0b,   // bf16
                                              void* __restrict__ outb,
                                              const int* __restrict__ rowptr,
                                              const int* __restrict__ cnt,
                                              const int* __restrict__ csr_src,
                                              const float* __restrict__ dinv) {
    int t = threadIdx.x;
    int lane = t & 63;
    int pair = lane >> 4;              // 0..3: edge sub-slot
    int dq = lane & 15;                // dims 8dq..8dq+7
    int v = blockIdx.x * 4 + (t >> 6); // 12500 * 4 == 50000 exactly
    int start = __builtin_amdgcn_readfirstlane(rowptr[v]);
    int c = __builtin_amdgcn_readfirstlane(cnt[v]);
    const int* cs = csr_src + start;

    // hoisted self/anchor loads overlap the edge loop
    float dv = dinv[v];
    uint4 qv = qin[v * 16 + dq];
    float4 hlo, hhi; uint4 hvb;
    if (LAST) {
        hlo = h0[v * 32 + 2 * dq];
        hhi = h0[v * 32 + 2 * dq + 1];
    } else {
        hvb = h0b[v * 16 + dq];
    }

    float a0 = 0.f, a1 = 0.f, a2 = 0.f, a3 = 0.f;
    float a4 = 0.f, a5 = 0.f, a6 = 0.f, a7 = 0.f;
    int i = 0;
    for (; i + 32 <= c; i += 32) {
        i4 ia = *(const i4*)(cs + i);
        i4 ib = *(const i4*)(cs + i + 4);
        i4 ic = *(const i4*)(cs + i + 8);
        i4 id = *(const i4*)(cs + i + 12);
        i4 ie = *(const i4*)(cs + i + 16);
        i4 ifq = *(const i4*)(cs + i + 20);
        i4 ig = *(const i4*)(cs + i + 24);
        i4 ih = *(const i4*)(cs + i + 28);
        int s0 = SEL(ia), s1 = SEL(ib), s2 = SEL(ic), s3 = SEL(id);
        int s4 = SEL(ie), s5 = SEL(ifq), s6 = SEL(ig), s7 = SEL(ih);
        uint4 g0 = qin[s0 * 16 + dq];
        uint4 g1 = qin[s1 * 16 + dq];
        uint4 g2 = qin[s2 * 16 + dq];
        uint4 g3 = qin[s3 * 16 + dq];
        uint4 g4 = qin[s4 * 16 + dq];
        uint4 g5 = qin[s5 * 16 + dq];
        uint4 g6 = qin[s6 * 16 + dq];
        uint4 g7 = qin[s7 * 16 + dq];
        ACC8(g0); ACC8(g1); ACC8(g2); ACC8(g3);
        ACC8(g4); ACC8(g5); ACC8(g6); ACC8(g7);
    }
    for (; i + 8 <= c; i += 8) {
        i4 ia = *(const i4*)(cs + i);
        i4 ib = *(const i4*)(cs + i + 4);
        int s0 = SEL(ia), s1 = SEL(ib);
        uint4 g0 = qin[s0 * 16 + dq];
        uint4 g1 = qin[s1 * 16 + dq];
        ACC8(g0); ACC8(g1);
    }
    for (; i < c; i += 4) {
        int e = i + pair;
        if (e < c) {
            uint4 g = qin[cs[e] * 16 + dq];
            ACC8(g);
        }
    }
    a0 += __shfl_xor(a0, 16); a0 += __shfl_xor(a0, 32);
    a1 += __shfl_xor(a1, 16); a1 += __shfl_xor(a1, 32);
    a2 += __shfl_xor(a2, 16); a2 += __shfl_xor(a2, 32);
    a3 += __shfl_xor(a3, 16); a3 += __shfl_xor(a3, 32);
    a4 += __shfl_xor(a4, 16); a4 += __shfl_xor(a4, 32);
    a5 += __shfl_xor(a5, 16); a5 += __shfl_xor(a5, 32);
    a6 += __shfl_xor(a6, 16); a6 += __shfl_xor(a6, 32);
    a7 += __shfl_xor(a7, 16); a7 += __shfl_xor(a7, 32);

    float s0 = a0 + bf2f_lo(qv.x), s1 = a1 + bf2f_hi(qv.x);
    float s2 = a2 + bf2f_lo(qv.y), s3 = a3 + bf2f_hi(qv.y);
    float s4 = a4 + bf2f_lo(qv.z), s5 = a5 + bf2f_hi(qv.z);
    float s6 = a6 + bf2f_lo(qv.w), s7 = a7 + bf2f_hi(qv.w);
    const float K = 1.f - ALPHA;

    if (LAST) {
        float h_0 = K * dv * s0 + ALPHA * hlo.x;
        float h_1 = K * dv * s1 + ALPHA * hlo.y;
        float h_2 = K * dv * s2 + ALPHA * hlo.z;
        float h_3 = K * dv * s3 + ALPHA * hlo.w;
        float h_4 = K * dv * s4 + ALPHA * hhi.x;
        float h_5 = K * dv * s5 + ALPHA * hhi.y;
        float h_6 = K * dv * s6 + ALPHA * hhi.z;
        float h_7 = K * dv * s7 + ALPHA * hhi.w;
        if (pair < 2) {
            float4 wv = (pair == 0) ? make_float4(h_0, h_1, h_2, h_3)
                                    : make_float4(h_4, h_5, h_6, h_7);
            ((float4*)outb)[v * 32 + 2 * dq + pair] = wv;
        }
    } else {
        float h_0 = K * dv * s0 + ALPHA * bf2f_lo(hvb.x);
        float h_1 = K * dv * s1 + ALPHA * bf2f_hi(hvb.x);
        float h_2 = K * dv * s2 + ALPHA * bf2f_lo(hvb.y);
        float h_3 = K * dv * s3 + ALPHA * bf2f_hi(hvb.y);
        float h_4 = K * dv * s4 + ALPHA * bf2f_lo(hvb.z);
        float h_5 = K * dv * s5 + ALPHA * bf2f_hi(hvb.z);
        float h_6 = K * dv * s6 + ALPHA * bf2f_lo(hvb.w);
        float h_7 = K * dv * s7 + ALPHA * bf2f_hi(hvb.w);
        if (pair == 0) {
            uint4 wv;
            wv.x = f2bf2(h_0 * dv, h_1 * dv);
            wv.y = f2bf2(h_2 * dv, h_3 * dv);
            wv.z = f2bf2(h_4 * dv, h_5 * dv);
            wv.w = f2bf2(h_6 * dv, h_7 * dv);
            ((uint4*)outb)[v * 16 + dq] = wv;
        }
    }
}

// ---------------- host ----------------

extern "C" void kernel_launch(void* const* d_in, const int* in_sizes, int n_in,
                              void* d_out, int out_size, void* d_ws, size_t ws_size,
                              hipStream_t stream) {
    const int*   x    = (const int*)d_in[0];             // [N, 9]
    const int*   ei   = (const int*)d_in[1];             // [2, E]
    const float* emb  = (const float*)d_in[2];           // [9, 119, 128]
    const float* Ws   = (const float*)d_in[3];           // [3, 128, 128]
    const float* bs   = (const float*)d_in[4];           // [3, 128]
    float* out = (float*)d_out;                          // [N, 128] f32

    const int* src = ei;
    const int* dst = ei + N_EDGES;

    // workspace carve-up (byte-based, 256B-aligned chunks); node buffers padded to NPAD
    char* w = (char*)d_ws;
    size_t off = 0;
    auto alloc = [&](size_t bytes) {
        void* p = w + off;
        off += (bytes + 255) & ~(size_t)255;
        return p;
    };
    float*  h0      = (float*)alloc((size_t)NPAD * EMB * 4);
    void*   hb      = alloc((size_t)NPAD * EMB * 2);   // bf16 MLP chain (in-place)
    void*   qA      = alloc((size_t)NPAD * EMB * 2);   // bf16
    void*   qB      = alloc((size_t)NPAD * EMB * 2);   // bf16
    void*   h0b     = alloc((size_t)NPAD * EMB * 2);   // bf16 copy of h0
    ushort* WT      = (ushort*)alloc((size_t)3 * 128 * 128 * 2);
    float*  dinv    = (float*)alloc((size_t)NPAD * 4);
    int*    cnt     = (int*)alloc(N_NODES * 4);
    int*    rowptr  = (int*)alloc(N_NODES * 4);
    int*    bsum    = (int*)alloc(256 * 4);
    int*    csr_src = (int*)alloc(N_EDGES * 4);
    int*    ord     = (int*)alloc(N_EDGES * 4);
    (void)ws_size; (void)n_in; (void)in_sizes; (void)out_size;

    const int NB_N  = (N_NODES + 255) / 256;   // 196
    const int NB_E  = (N_EDGES + 255) / 256;   // 3125
    const int NB_EN = N_NODES / 4;             // 12500 (encode, exact)
    const int NB_M  = NPAD / 64;               // 782 (mfma mlp)
    const int NB_P  = N_NODES / 4;             // 12500 (prop, exact)

    // CSR build
    k_zero<<<NB_N, 256, 0, stream>>>(cnt);
    k_count<<<NB_E, 256, 0, stream>>>(dst, cnt, ord);
    k_scan1<<<NB_N, 256, 0, stream>>>(cnt, rowptr, bsum, dinv);
    k_scan2<<<1, 256, 0, stream>>>(bsum, NB_N);
    k_scan3<<<NB_N, 256, 0, stream>>>(rowptr, bsum);
    k_fill<<<NB_E, 256, 0, stream>>>(src, dst, ord, rowptr, csr_src);

    // W transpose->bf16, encoder->bf16, 3 MFMA MLP layers (in-place on hb)
    k_wprep<<<384, 128, 0, stream>>>(Ws, WT);
    k_encode<<<NB_EN, 256, 0, stream>>>(x, emb, (unsigned*)hb);
    k_mlp_mfma<1, 0><<<NB_M, 256, 0, stream>>>(
        (const uint4*)hb, (uint4*)hb, (const uint4*)(WT + 0 * 128 * 128),
        bs + 0 * EMB, nullptr, nullptr, nullptr, nullptr);
    k_mlp_mfma<1, 0><<<NB_M, 256, 0, stream>>>(
        (const uint4*)hb, (uint4*)hb, (const uint4*)(WT + 1 * 128 * 128),
        bs + 1 * EMB, nullptr, nullptr, nullptr, nullptr);
    k_mlp_mfma<0, 1><<<NB_M, 256, 0, stream>>>(
        (const uint4*)hb, nullptr, (const uint4*)(WT + 2 * 128 * 128),
        bs + 2 * EMB, dinv, h0, (ushort*)qA, (ushort*)h0b);

    // 10 propagation iterations on bf16 q; last writes f32 h to d_out
    const uint4* qin = (const uint4*)qA;
    for (int i = 0; i < NITER; ++i) {
        if (i == NITER - 1) {
            k_prop<1><<<NB_P, 256, 0, stream>>>(qin, (const float4*)h0,
                                                (const uint4*)h0b, out,
                                                rowptr, cnt, csr_src, dinv);
        } else {
            void* qo = (i & 1) ? qA : qB;
            k_prop<0><<<NB_P, 256, 0, stream>>>(qin, (const float4*)h0,
                                                (const uint4*)h0b, qo,
                                                rowptr, cnt, csr_src, dinv);
            qin = (const uint4*)qo;
        }
    }
}

// Round 10
// 538.278 us; speedup vs baseline: 3.5958x; 1.0293x over previous
//
#include <hip/hip_runtime.h>

#define N_NODES 50000
#define NPAD    50048   // 782 * 64, MFMA-tile padded
#define ZROW    50000   // dedicated all-zero row for clamped gather slots
#define N_EDGES 800000
#define EMB 128
#define NFEAT 9
#define VOCAB 119
#define NITER 10
#define ALPHA 0.1f

typedef __attribute__((ext_vector_type(8))) short bf16x8;
typedef __attribute__((ext_vector_type(4))) float f32x4;

// ---------------- bf16 helpers (manual RNE) ----------------

__device__ inline unsigned int f2bf1(float x) {
    union { float f; unsigned u; } v; v.f = x;
    unsigned r = v.u + 0x7fffu + ((v.u >> 16) & 1u);
    return r >> 16;
}
__device__ inline unsigned int f2bf2(float lo, float hi) {
    return f2bf1(lo) | (f2bf1(hi) << 16);
}
__device__ inline float bf2f_lo(unsigned u) {
    union { unsigned u; float f; } v; v.u = u << 16; return v.f;
}
__device__ inline float bf2f_hi(unsigned u) {
    union { unsigned u; float f; } v; v.u = u & 0xffff0000u; return v.f;
}

// unaligned-friendly int4 (CSR rows start at arbitrary dword offsets)
struct __attribute__((aligned(4))) i4 { int x, y, z, w; };

// ---------------- CSR build ----------------

__global__ void k_zero(int* __restrict__ cnt) {
    int i = blockIdx.x * blockDim.x + threadIdx.x;
    if (i < N_NODES) cnt[i] = 0;
}

__global__ void k_count(const int* __restrict__ dst, int* __restrict__ cnt,
                        int* __restrict__ ord) {
    int e = blockIdx.x * blockDim.x + threadIdx.x;
    if (e < N_EDGES) ord[e] = atomicAdd(&cnt[dst[e]], 1);
}

__global__ void k_scan1(const int* __restrict__ cnt, int* __restrict__ rowptr,
                        int* __restrict__ bsum, float* __restrict__ dinv) {
    __shared__ int s[256];
    int t = threadIdx.x;
    int idx = blockIdx.x * 256 + t;
    int v = (idx < N_NODES) ? cnt[idx] : 0;
    if (idx < N_NODES) dinv[idx] = rsqrtf((float)(v + 1));  // +1 self loop
    s[t] = v; __syncthreads();
    for (int off = 1; off < 256; off <<= 1) {
        int add = (t >= off) ? s[t - off] : 0;
        __syncthreads();
        s[t] += add;
        __syncthreads();
    }
    if (idx < N_NODES) rowptr[idx] = s[t] - v;   // exclusive
    if (t == 255) bsum[blockIdx.x] = s[255];     // block total
}

__global__ void k_scan2(int* __restrict__ bsum, int nb) {
    __shared__ int s[256];
    int t = threadIdx.x;
    int v = (t < nb) ? bsum[t] : 0;
    s[t] = v; __syncthreads();
    for (int off = 1; off < 256; off <<= 1) {
        int add = (t >= off) ? s[t - off] : 0;
        __syncthreads();
        s[t] += add;
        __syncthreads();
    }
    if (t < nb) bsum[t] = s[t] - v;              // exclusive block offsets
}

__global__ void k_scan3(int* __restrict__ rowptr, const int* __restrict__ bsum) {
    int idx = blockIdx.x * 256 + threadIdx.x;
    if (idx < N_NODES) rowptr[idx] += bsum[blockIdx.x];
}

__global__ void k_fill(const int* __restrict__ src, const int* __restrict__ dst,
                       const int* __restrict__ ord, const int* __restrict__ rowptr,
                       int* __restrict__ csr_src) {
    int e = blockIdx.x * blockDim.x + threadIdx.x;
    if (e < N_EDGES) {
        csr_src[rowptr[dst[e]] + ord[e]] = src[e];
    }
}

// zero the pad rows (incl. ZROW) of both q buffers: 48 rows * 16 uint4 * 2
__global__ void k_zpad(uint4* __restrict__ qA, uint4* __restrict__ qB) {
    int t = threadIdx.x;   // 256 threads, 1 block
    const uint4 z = make_uint4(0u, 0u, 0u, 0u);
    for (int i = t; i < (NPAD - N_NODES) * 16; i += 256) {
        qA[(size_t)N_NODES * 16 + i] = z;
        qB[(size_t)N_NODES * 16 + i] = z;
    }
}

// ---------------- W prep: WT[l][n][k] = bf16(W[l][k][n]) ----------------

__global__ void k_wprep(const float* __restrict__ W, ushort* __restrict__ WT) {
    int l = blockIdx.x >> 7;        // layer 0..2
    int n = blockIdx.x & 127;
    int k = threadIdx.x;            // 128 threads
    WT[(l * 128 + n) * 128 + k] = (ushort)f2bf1(W[(l * 128 + k) * 128 + n]);
}

// ---------------- encoder -> bf16 ----------------

__global__ void k_encode(const int* __restrict__ x, const float* __restrict__ emb,
                         unsigned* __restrict__ hb) {
    int t = threadIdx.x;
    int sub = t >> 6;                   // node 0..3
    int dq = t & 63;                    // dim pair
    int n = blockIdx.x * 4 + sub;       // grid 12500 -> exact 50000
    const int* xr = x + n * NFEAT;
    float s0 = 0.f, s1 = 0.f;
#pragma unroll
    for (int f = 0; f < NFEAT; ++f) {
        const float2 e = *(const float2*)&emb[(f * VOCAB + xr[f]) * EMB + 2 * dq];
        s0 += e.x; s1 += e.y;
    }
    hb[n * 64 + dq] = f2bf2(s0, s1);
}

// ---------------- MLP via MFMA: 64 nodes/block, 4 waves ----------------

template <int RELU, int WQ>
__global__ __launch_bounds__(256) void k_mlp_mfma(
        const uint4* __restrict__ inb,     // bf16 [NPAD][128], row = 16 uint4
        uint4* __restrict__ outb,          // bf16 out (may == inb; per-block in-place safe)
        const uint4* __restrict__ WT4,     // bf16 [128][128] n-major
        const float* __restrict__ bias,
        const float* __restrict__ dinv,
        float* __restrict__ h0out,         // WQ: f32
        ushort* __restrict__ q0out,        // WQ: bf16 dinv*h
        ushort* __restrict__ h0bout) {     // WQ: bf16 h
    int t = threadIdx.x;
    int w = t >> 6;
    int l = t & 63;
    int lr = l & 15;       // A-row / B-col / C-col within tile
    int kg = l >> 4;       // k-group 0..3
    int base = blockIdx.x * 64 + w * 16;
    union U { uint4 u; bf16x8 b; };

    int arow = base + lr;
    bf16x8 afrag[4];
#pragma unroll
    for (int kc = 0; kc < 4; ++kc) {
        U cu; cu.u = inb[arow * 16 + kc * 4 + kg];
        afrag[kc] = cu.b;
    }

    f32x4 acc[8];
#pragma unroll
    for (int nt = 0; nt < 8; ++nt) {
        float bv = bias[nt * 16 + lr];
        acc[nt] = (f32x4){bv, bv, bv, bv};
    }

#pragma unroll
    for (int kc = 0; kc < 4; ++kc) {
#pragma unroll
        for (int nt = 0; nt < 8; ++nt) {
            U cu; cu.u = WT4[(nt * 16 + lr) * 16 + kc * 4 + kg];
            acc[nt] = __builtin_amdgcn_mfma_f32_16x16x32_bf16(afrag[kc], cu.b,
                                                              acc[nt], 0, 0, 0);
        }
    }

    int orow = base + kg * 4;   // rows orow..orow+3 (reg index r)
    float dv[4];
    if (WQ) {
#pragma unroll
        for (int r = 0; r < 4; ++r) dv[r] = dinv[orow + r];
    }
#pragma unroll
    for (int nt = 0; nt < 8; ++nt) {
        int n = nt * 16 + lr;
#pragma unroll
        for (int r = 0; r < 4; ++r) {
            float val = acc[nt][r];
            if (RELU) val = fmaxf(val, 0.f);
            if (WQ) {
                h0out[(orow + r) * 128 + n] = val;
                q0out[(orow + r) * 128 + n] = (ushort)f2bf1(val * dv[r]);
                h0bout[(orow + r) * 128 + n] = (ushort)f2bf1(val);
            } else {
                ((ushort*)outb)[(orow + r) * 128 + n] = (ushort)f2bf1(val);
            }
        }
    }
}

// ---------------- propagation on bf16 q = dinv*h ----------------
// Tiered static fast paths: deg<=16 -> 4 gathers issued up-front; deg<=32 -> 8;
// else loop. Empty slots clamp to ZROW (a zeroed pad row), so no masking cost.

#define ACC8(g) \
    a0 += bf2f_lo((g).x); a1 += bf2f_hi((g).x); \
    a2 += bf2f_lo((g).y); a3 += bf2f_hi((g).y); \
    a4 += bf2f_lo((g).z); a5 += bf2f_hi((g).z); \
    a6 += bf2f_lo((g).w); a7 += bf2f_hi((g).w);

#define SEL(iv) (pair == 0 ? (iv).x : pair == 1 ? (iv).y : pair == 2 ? (iv).z : (iv).w)

template <int LAST>
__global__ __launch_bounds__(256) void k_prop(const uint4* __restrict__ qin,
                                              const float4* __restrict__ h0,   // f32 (LAST)
                                              const uint4* __restrict__ h0b,   // bf16
                                              void* __restrict__ outb,
                                              const int* __restrict__ rowptr,
                                              const int* __restrict__ cnt,
                                              const int* __restrict__ csr_src,
                                              const float* __restrict__ dinv) {
    int t = threadIdx.x;
    int lane = t & 63;
    int pair = lane >> 4;              // 0..3: edge sub-slot
    int dq = lane & 15;                // dims 8dq..8dq+7
    int v = blockIdx.x * 4 + (t >> 6); // 12500 * 4 == 50000 exactly
    int start = __builtin_amdgcn_readfirstlane(rowptr[v]);
    int c = __builtin_amdgcn_readfirstlane(cnt[v]);
    const int* cs = csr_src + start;

    // hoisted self/anchor loads overlap the edge gathers
    float dv = dinv[v];
    uint4 qv = qin[v * 16 + dq];
    float4 hlo, hhi; uint4 hvb;
    if (LAST) {
        hlo = h0[v * 32 + 2 * dq];
        hhi = h0[v * 32 + 2 * dq + 1];
    } else {
        hvb = h0b[v * 16 + dq];
    }

    float a0 = 0.f, a1 = 0.f, a2 = 0.f, a3 = 0.f;
    float a4 = 0.f, a5 = 0.f, a6 = 0.f, a7 = 0.f;

    if (c <= 16) {
        // csr_src padded +32 ints -> over-read is safe; empty slots -> ZROW
        i4 ia = *(const i4*)(cs + 0);
        i4 ib = *(const i4*)(cs + 4);
        i4 ic = *(const i4*)(cs + 8);
        i4 id = *(const i4*)(cs + 12);
        int s0 = (0  + pair < c) ? SEL(ia) : ZROW;
        int s1 = (4  + pair < c) ? SEL(ib) : ZROW;
        int s2 = (8  + pair < c) ? SEL(ic) : ZROW;
        int s3 = (12 + pair < c) ? SEL(id) : ZROW;
        uint4 g0 = qin[s0 * 16 + dq];
        uint4 g1 = qin[s1 * 16 + dq];
        uint4 g2 = qin[s2 * 16 + dq];
        uint4 g3 = qin[s3 * 16 + dq];
        ACC8(g0); ACC8(g1); ACC8(g2); ACC8(g3);
    } else if (c <= 32) {
        i4 ia = *(const i4*)(cs + 0);
        i4 ib = *(const i4*)(cs + 4);
        i4 ic = *(const i4*)(cs + 8);
        i4 id = *(const i4*)(cs + 12);
        i4 ie = *(const i4*)(cs + 16);
        i4 ifq = *(const i4*)(cs + 20);
        i4 ig = *(const i4*)(cs + 24);
        i4 ih = *(const i4*)(cs + 28);
        int s0 = (0  + pair < c) ? SEL(ia) : ZROW;
        int s1 = (4  + pair < c) ? SEL(ib) : ZROW;
        int s2 = (8  + pair < c) ? SEL(ic) : ZROW;
        int s3 = (12 + pair < c) ? SEL(id) : ZROW;
        int s4 = (16 + pair < c) ? SEL(ie) : ZROW;
        int s5 = (20 + pair < c) ? SEL(ifq) : ZROW;
        int s6 = (24 + pair < c) ? SEL(ig) : ZROW;
        int s7 = (28 + pair < c) ? SEL(ih) : ZROW;
        uint4 g0 = qin[s0 * 16 + dq];
        uint4 g1 = qin[s1 * 16 + dq];
        uint4 g2 = qin[s2 * 16 + dq];
        uint4 g3 = qin[s3 * 16 + dq];
        uint4 g4 = qin[s4 * 16 + dq];
        uint4 g5 = qin[s5 * 16 + dq];
        uint4 g6 = qin[s6 * 16 + dq];
        uint4 g7 = qin[s7 * 16 + dq];
        ACC8(g0); ACC8(g1); ACC8(g2); ACC8(g3);
        ACC8(g4); ACC8(g5); ACC8(g6); ACC8(g7);
    } else {
        int i = 0;
        for (; i + 32 <= c; i += 32) {
            i4 ia = *(const i4*)(cs + i);
            i4 ib = *(const i4*)(cs + i + 4);
            i4 ic = *(const i4*)(cs + i + 8);
            i4 id = *(const i4*)(cs + i + 12);
            i4 ie = *(const i4*)(cs + i + 16);
            i4 ifq = *(const i4*)(cs + i + 20);
            i4 ig = *(const i4*)(cs + i + 24);
            i4 ih = *(const i4*)(cs + i + 28);
            int s0 = SEL(ia), s1 = SEL(ib), s2 = SEL(ic), s3 = SEL(id);
            int s4 = SEL(ie), s5 = SEL(ifq), s6 = SEL(ig), s7 = SEL(ih);
            uint4 g0 = qin[s0 * 16 + dq];
            uint4 g1 = qin[s1 * 16 + dq];
            uint4 g2 = qin[s2 * 16 + dq];
            uint4 g3 = qin[s3 * 16 + dq];
            uint4 g4 = qin[s4 * 16 + dq];
            uint4 g5 = qin[s5 * 16 + dq];
            uint4 g6 = qin[s6 * 16 + dq];
            uint4 g7 = qin[s7 * 16 + dq];
            ACC8(g0); ACC8(g1); ACC8(g2); ACC8(g3);
            ACC8(g4); ACC8(g5); ACC8(g6); ACC8(g7);
        }
        // masked tail: up to 32 edges via ZROW clamp
        if (i < c) {
            i4 ia = *(const i4*)(cs + i);
            i4 ib = *(const i4*)(cs + i + 4);
            i4 ic = *(const i4*)(cs + i + 8);
            i4 id = *(const i4*)(cs + i + 12);
            i4 ie = *(const i4*)(cs + i + 16);
            i4 ifq = *(const i4*)(cs + i + 20);
            i4 ig = *(const i4*)(cs + i + 24);
            i4 ih = *(const i4*)(cs + i + 28);
            int s0 = (i + 0  + pair < c) ? SEL(ia) : ZROW;
            int s1 = (i + 4  + pair < c) ? SEL(ib) : ZROW;
            int s2 = (i + 8  + pair < c) ? SEL(ic) : ZROW;
            int s3 = (i + 12 + pair < c) ? SEL(id) : ZROW;
            int s4 = (i + 16 + pair < c) ? SEL(ie) : ZROW;
            int s5 = (i + 20 + pair < c) ? SEL(ifq) : ZROW;
            int s6 = (i + 24 + pair < c) ? SEL(ig) : ZROW;
            int s7 = (i + 28 + pair < c) ? SEL(ih) : ZROW;
            uint4 g0 = qin[s0 * 16 + dq];
            uint4 g1 = qin[s1 * 16 + dq];
            uint4 g2 = qin[s2 * 16 + dq];
            uint4 g3 = qin[s3 * 16 + dq];
            uint4 g4 = qin[s4 * 16 + dq];
            uint4 g5 = qin[s5 * 16 + dq];
            uint4 g6 = qin[s6 * 16 + dq];
            uint4 g7 = qin[s7 * 16 + dq];
            ACC8(g0); ACC8(g1); ACC8(g2); ACC8(g3);
            ACC8(g4); ACC8(g5); ACC8(g6); ACC8(g7);
        }
    }

    a0 += __shfl_xor(a0, 16); a0 += __shfl_xor(a0, 32);
    a1 += __shfl_xor(a1, 16); a1 += __shfl_xor(a1, 32);
    a2 += __shfl_xor(a2, 16); a2 += __shfl_xor(a2, 32);
    a3 += __shfl_xor(a3, 16); a3 += __shfl_xor(a3, 32);
    a4 += __shfl_xor(a4, 16); a4 += __shfl_xor(a4, 32);
    a5 += __shfl_xor(a5, 16); a5 += __shfl_xor(a5, 32);
    a6 += __shfl_xor(a6, 16); a6 += __shfl_xor(a6, 32);
    a7 += __shfl_xor(a7, 16); a7 += __shfl_xor(a7, 32);

    float s0 = a0 + bf2f_lo(qv.x), s1 = a1 + bf2f_hi(qv.x);
    float s2 = a2 + bf2f_lo(qv.y), s3 = a3 + bf2f_hi(qv.y);
    float s4 = a4 + bf2f_lo(qv.z), s5 = a5 + bf2f_hi(qv.z);
    float s6 = a6 + bf2f_lo(qv.w), s7 = a7 + bf2f_hi(qv.w);
    const float K = 1.f - ALPHA;

    if (LAST) {
        float h_0 = K * dv * s0 + ALPHA * hlo.x;
        float h_1 = K * dv * s1 + ALPHA * hlo.y;
        float h_2 = K * dv * s2 + ALPHA * hlo.z;
        float h_3 = K * dv * s3 + ALPHA * hlo.w;
        float h_4 = K * dv * s4 + ALPHA * hhi.x;
        float h_5 = K * dv * s5 + ALPHA * hhi.y;
        float h_6 = K * dv * s6 + ALPHA * hhi.z;
        float h_7 = K * dv * s7 + ALPHA * hhi.w;
        if (pair < 2) {
            float4 wv = (pair == 0) ? make_float4(h_0, h_1, h_2, h_3)
                                    : make_float4(h_4, h_5, h_6, h_7);
            ((float4*)outb)[v * 32 + 2 * dq + pair] = wv;
        }
    } else {
        float h_0 = K * dv * s0 + ALPHA * bf2f_lo(hvb.x);
        float h_1 = K * dv * s1 + ALPHA * bf2f_hi(hvb.x);
        float h_2 = K * dv * s2 + ALPHA * bf2f_lo(hvb.y);
        float h_3 = K * dv * s3 + ALPHA * bf2f_hi(hvb.y);
        float h_4 = K * dv * s4 + ALPHA * bf2f_lo(hvb.z);
        float h_5 = K * dv * s5 + ALPHA * bf2f_hi(hvb.z);
        float h_6 = K * dv * s6 + ALPHA * bf2f_lo(hvb.w);
        float h_7 = K * dv * s7 + ALPHA * bf2f_hi(hvb.w);
        if (pair == 0) {
            uint4 wv;
            wv.x = f2bf2(h_0 * dv, h_1 * dv);
            wv.y = f2bf2(h_2 * dv, h_3 * dv);
            wv.z = f2bf2(h_4 * dv, h_5 * dv);
            wv.w = f2bf2(h_6 * dv, h_7 * dv);
            ((uint4*)outb)[v * 16 + dq] = wv;
        }
    }
}

// ---------------- host ----------------

extern "C" void kernel_launch(void* const* d_in, const int* in_sizes, int n_in,
                              void* d_out, int out_size, void* d_ws, size_t ws_size,
                              hipStream_t stream) {
    const int*   x    = (const int*)d_in[0];             // [N, 9]
    const int*   ei   = (const int*)d_in[1];             // [2, E]
    const float* emb  = (const float*)d_in[2];           // [9, 119, 128]
    const float* Ws   = (const float*)d_in[3];           // [3, 128, 128]
    const float* bs   = (const float*)d_in[4];           // [3, 128]
    float* out = (float*)d_out;                          // [N, 128] f32

    const int* src = ei;
    const int* dst = ei + N_EDGES;

    // workspace carve-up (byte-based, 256B-aligned chunks); node buffers padded to NPAD
    char* w = (char*)d_ws;
    size_t off = 0;
    auto alloc = [&](size_t bytes) {
        void* p = w + off;
        off += (bytes + 255) & ~(size_t)255;
        return p;
    };
    float*  h0      = (float*)alloc((size_t)NPAD * EMB * 4);
    void*   hb      = alloc((size_t)NPAD * EMB * 2);   // bf16 MLP chain (in-place)
    void*   qA      = alloc((size_t)NPAD * EMB * 2);   // bf16
    void*   qB      = alloc((size_t)NPAD * EMB * 2);   // bf16
    void*   h0b     = alloc((size_t)NPAD * EMB * 2);   // bf16 copy of h0
    ushort* WT      = (ushort*)alloc((size_t)3 * 128 * 128 * 2);
    float*  dinv    = (float*)alloc((size_t)NPAD * 4);
    int*    cnt     = (int*)alloc(N_NODES * 4);
    int*    rowptr  = (int*)alloc(N_NODES * 4);
    int*    bsum    = (int*)alloc(256 * 4);
    int*    csr_src = (int*)alloc((N_EDGES + 32) * 4);  // +32 pad for fast-path over-read
    int*    ord     = (int*)alloc(N_EDGES * 4);
    (void)ws_size; (void)n_in; (void)in_sizes; (void)out_size;

    const int NB_N  = (N_NODES + 255) / 256;   // 196
    const int NB_E  = (N_EDGES + 255) / 256;   // 3125
    const int NB_EN = N_NODES / 4;             // 12500 (encode, exact)
    const int NB_M  = NPAD / 64;               // 782 (mfma mlp)
    const int NB_P  = N_NODES / 4;             // 12500 (prop, exact)

    // CSR build
    k_zero<<<NB_N, 256, 0, stream>>>(cnt);
    k_count<<<NB_E, 256, 0, stream>>>(dst, cnt, ord);
    k_scan1<<<NB_N, 256, 0, stream>>>(cnt, rowptr, bsum, dinv);
    k_scan2<<<1, 256, 0, stream>>>(bsum, NB_N);
    k_scan3<<<NB_N, 256, 0, stream>>>(rowptr, bsum);
    k_fill<<<NB_E, 256, 0, stream>>>(src, dst, ord, rowptr, csr_src);

    // W transpose->bf16, encoder->bf16, 3 MFMA MLP layers (in-place on hb)
    k_wprep<<<384, 128, 0, stream>>>(Ws, WT);
    k_encode<<<NB_EN, 256, 0, stream>>>(x, emb, (unsigned*)hb);
    k_mlp_mfma<1, 0><<<NB_M, 256, 0, stream>>>(
        (const uint4*)hb, (uint4*)hb, (const uint4*)(WT + 0 * 128 * 128),
        bs + 0 * EMB, nullptr, nullptr, nullptr, nullptr);
    k_mlp_mfma<1, 0><<<NB_M, 256, 0, stream>>>(
        (const uint4*)hb, (uint4*)hb, (const uint4*)(WT + 1 * 128 * 128),
        bs + 1 * EMB, nullptr, nullptr, nullptr, nullptr);
    k_mlp_mfma<0, 1><<<NB_M, 256, 0, stream>>>(
        (const uint4*)hb, nullptr, (const uint4*)(WT + 2 * 128 * 128),
        bs + 2 * EMB, dinv, h0, (ushort*)qA, (ushort*)h0b);

    // zero pad rows (incl. ZROW) AFTER the MLP wrote garbage there
    k_zpad<<<1, 256, 0, stream>>>((uint4*)qA, (uint4*)qB);

    // 10 propagation iterations on bf16 q; last writes f32 h to d_out
    const uint4* qin = (const uint4*)qA;
    for (int i = 0; i < NITER; ++i) {
        if (i == NITER - 1) {
            k_prop<1><<<NB_P, 256, 0, stream>>>(qin, (const float4*)h0,
                                                (const uint4*)h0b, out,
                                                rowptr, cnt, csr_src, dinv);
        } else {
            void* qo = (i & 1) ? qA : qB;
            k_prop<0><<<NB_P, 256, 0, stream>>>(qin, (const float4*)h0,
                                                (const uint4*)h0b, qo,
                                                rowptr, cnt, csr_src, dinv);
            qin = (const uint4*)qo;
        }
    }
}